// Round 8
// baseline (226.984 us; speedup 1.0000x reference)
//
#include <hip/hip_runtime.h>

// ---------- types & helpers ----------
typedef unsigned short u16;
typedef float   f32x4  __attribute__((ext_vector_type(4)));
typedef short   short8 __attribute__((ext_vector_type(8)));
typedef __bf16  bf16x8 __attribute__((ext_vector_type(8)));
typedef float   float4v __attribute__((ext_vector_type(4)));
typedef unsigned short u16x4 __attribute__((ext_vector_type(4)));

// native HW bf16 convert (RNE, v_cvt_pk_bf16_f32) — do not hand-roll (T12/m240)
static __device__ __forceinline__ u16 f2b(float f) {
  return __builtin_bit_cast(u16, (__bf16)f);
}
static __device__ __forceinline__ float b2f(u16 h) {
  union { unsigned u; float f; } v; v.u = ((unsigned)h) << 16;
  return v.f;
}
static __device__ __forceinline__ f32x4 mfma_bf16(short8 a, short8 b, f32x4 c) {
  return __builtin_amdgcn_mfma_f32_16x16x32_bf16(
      __builtin_bit_cast(bf16x8, a), __builtin_bit_cast(bf16x8, b), c, 0, 0, 0);
}
// async global->LDS, 16B per lane; lds ptr must be wave-uniform base (HW adds lane*16)
static __device__ __forceinline__ void gload_lds16(const u16* g, u16* l) {
  __builtin_amdgcn_global_load_lds(
      (const __attribute__((address_space(1))) unsigned int*)g,
      (__attribute__((address_space(3))) unsigned int*)l, 16, 0, 0);
}

// ---------- problem constants ----------
#define BB 2
#define TT 2048
#define DD 2048
#define NH 16
#define NKVH 4
#define HD 128
#define MM (BB * TT)          // 4096 rows
#define QSTR 3072             // fused QKV projection row: [Q(2048) | K(512) | V(512)]
#define QSCALE 0.08838834764831845f

// ---------- fused fp32 -> bf16 convert (all 5 tensors, 1 launch) ----------
#define N4_X   ((MM * DD) / 4)
#define N4_WQ  ((DD * DD) / 4)
#define N4_WKV ((NKVH * HD * DD) / 4)
#define N4_WO  ((DD * DD) / 4)
#define N4_TOT (N4_X + N4_WQ + 2 * N4_WKV + N4_WO)

__global__ __launch_bounds__(256) void cvt_all(const float* __restrict__ x,
                                               const float* __restrict__ wq,
                                               const float* __restrict__ wk,
                                               const float* __restrict__ wv,
                                               const float* __restrict__ wo,
                                               u16* __restrict__ xb,
                                               u16* __restrict__ wqkvb,
                                               u16* __restrict__ wob) {
  int stride = gridDim.x * blockDim.x;
  for (int i = blockIdx.x * blockDim.x + threadIdx.x; i < N4_TOT; i += stride) {
    const float4v* src;
    u16x4* dst;
    int off;
    if (i < N4_X) {
      src = (const float4v*)x; dst = (u16x4*)xb; off = i;
    } else if (i < N4_X + N4_WQ) {
      src = (const float4v*)wq; dst = (u16x4*)wqkvb; off = i - N4_X;
    } else if (i < N4_X + N4_WQ + N4_WKV) {
      src = (const float4v*)wk; dst = (u16x4*)wqkvb + N4_WQ; off = i - (N4_X + N4_WQ);
    } else if (i < N4_X + N4_WQ + 2 * N4_WKV) {
      src = (const float4v*)wv; dst = (u16x4*)wqkvb + N4_WQ + N4_WKV;
      off = i - (N4_X + N4_WQ + N4_WKV);
    } else {
      src = (const float4v*)wo; dst = (u16x4*)wob; off = i - (N4_X + N4_WQ + 2 * N4_WKV);
    }
    float4v v = src[off];
    u16x4 o;
    o[0] = f2b(v[0]); o[1] = f2b(v[1]); o[2] = f2b(v[2]); o[3] = f2b(v[3]);
    dst[off] = o;
  }
}

// ---------- RoPE on K only (Q-rope is fused into the attention prologue) ----------
__global__ __launch_bounds__(256) void rope_k(u16* __restrict__ K,
                                              const float* __restrict__ rope) {
  int idx = blockIdx.x * 256 + threadIdx.x;
  int i  = idx & 63;
  int h  = (idx >> 6) & (NKVH - 1);
  int bt = idx >> 8;
  int t  = bt & (TT - 1);
  size_t base = (size_t)bt * QSTR + h * HD + i;
  float x1 = b2f(K[base]);
  float x2 = b2f(K[base + 64]);
  float c = rope[t * 128 + 2 * i];
  float s = rope[t * 128 + 2 * i + 1];
  K[base]      = f2b(x1 * c - x2 * s);
  K[base + 64] = f2b(x1 * s + x2 * c);
}

// ---------- 8-phase-style 256x256 GEMM (QKV projection) ----------
// C[M,N] = A[M,K] * W[N,K]^T, bf16 out. BM=BN=256, BK=64, 8 waves (2Mx4N),
// 128x64 per wave. 128KB double-buffered LDS. Counted vmcnt(8): one full
// tile of gload_lds stays in flight across the previous tile's compute
// (never drained in-loop). Raw s_barrier (no __syncthreads vmcnt drain).
// Conflict-free LDS via pre-swizzled SOURCE + XOR on READ (rule #21):
// element (r,c) lives at granule r*8 + ((c>>3) ^ (r&7)).
__global__ __launch_bounds__(512, 2) void gemm_qkv(const u16* __restrict__ A,
                                                   const u16* __restrict__ W,
                                                   u16* __restrict__ C,
                                                   int M, int N, int K) {
  __shared__ __align__(16) u16 As[2][2][128 * 64];  // [buf][half][r*64+swz]
  __shared__ __align__(16) u16 Ws[2][2][128 * 64];

  const int tid = threadIdx.x, lane = tid & 63, wid = tid >> 6;
  const int wm = wid >> 2, wn = wid & 3;
  const int l15 = lane & 15, lh = lane >> 4;

  // T1 bijective XCD swizzle (nwg = 192, %8 == 0)
  const int nwg = gridDim.x * gridDim.y;
  const int lin = blockIdx.y * gridDim.x + blockIdx.x;
  const int swz = (lin & 7) * (nwg >> 3) + (lin >> 3);
  const int brow = (swz / gridDim.x) * 256, bcol = (swz % gridDim.x) * 256;

  // staging sources, pre-swizzled: slot (half mh, instance i) row =
  // mh*128 + i*64 + wid*8 + (lane>>3); source colgroup = (lane&7)^(lane>>3)
  const int srp = wid * 8 + (lane >> 3);
  const int gsw = ((lane & 7) ^ (lane >> 3)) << 3;
  const u16* sa[2][2];
  const u16* sw[2][2];
#pragma unroll
  for (int mh = 0; mh < 2; ++mh)
#pragma unroll
    for (int i = 0; i < 2; ++i) {
      sa[mh][i] = A + (size_t)(brow + mh * 128 + i * 64 + srp) * K + gsw;
      sw[mh][i] = W + (size_t)(bcol + mh * 128 + i * 64 + srp) * K + gsw;
    }

  f32x4 acc[8][4];
#pragma unroll
  for (int mi = 0; mi < 8; ++mi)
#pragma unroll
    for (int ni = 0; ni < 4; ++ni) acc[mi][ni] = (f32x4)0.0f;

  const int nk = K >> 6;  // 64-wide K tiles

  auto issue = [&](int t, int p) {
#pragma unroll
    for (int mh = 0; mh < 2; ++mh)
#pragma unroll
      for (int i = 0; i < 2; ++i) {
        gload_lds16(sa[mh][i] + t * 64, &As[p][mh][i * 4096 + wid * 512]);
        gload_lds16(sw[mh][i] + t * 64, &Ws[p][mh][i * 4096 + wid * 512]);
      }
  };

  issue(0, 0);
  for (int t = 0; t < nk; ++t) {
    const int p = t & 1;
    if (t + 1 < nk) {
      issue(t + 1, p ^ 1);  // next tile: 8 loads stay in flight across compute
      asm volatile("s_waitcnt vmcnt(8)" ::: "memory");  // tile t's 8 landed
    } else {
      asm volatile("s_waitcnt vmcnt(0)" ::: "memory");
    }
    __builtin_amdgcn_sched_barrier(0);
    __builtin_amdgcn_s_barrier();   // B1: all waves' tile-t stages visible
    __builtin_amdgcn_sched_barrier(0);

    const u16* Ab = &As[p][wm][0];
    const u16* Wb = &Ws[p][wn >> 1][0];
    const int wrow = (wn & 1) * 64;

    short8 af[4][2], bf[2][2];
    // ---- phase 0: A lo half-frags + B cols 0..31
#pragma unroll
    for (int mi = 0; mi < 4; ++mi)
#pragma unroll
      for (int ks = 0; ks < 2; ++ks) {
        int rh = mi * 16 + l15;
        af[mi][ks] = *(const short8*)&Ab[rh * 64 + (((ks * 4 + lh) ^ (rh & 7)) << 3)];
      }
#pragma unroll
    for (int ni = 0; ni < 2; ++ni)
#pragma unroll
      for (int ks = 0; ks < 2; ++ks) {
        int rh = wrow + ni * 16 + l15;
        bf[ni][ks] = *(const short8*)&Wb[rh * 64 + (((ks * 4 + lh) ^ (rh & 7)) << 3)];
      }
    __builtin_amdgcn_s_setprio(1);
#pragma unroll
    for (int mi = 0; mi < 4; ++mi)
#pragma unroll
      for (int ni = 0; ni < 2; ++ni)
#pragma unroll
        for (int ks = 0; ks < 2; ++ks)
          acc[mi][ni] = mfma_bf16(af[mi][ks], bf[ni][ks], acc[mi][ni]);
    __builtin_amdgcn_s_setprio(0);
    __builtin_amdgcn_s_barrier();
    // ---- phase 1: B cols 32..63 (A kept)
#pragma unroll
    for (int ni = 0; ni < 2; ++ni)
#pragma unroll
      for (int ks = 0; ks < 2; ++ks) {
        int rh = wrow + (2 + ni) * 16 + l15;
        bf[ni][ks] = *(const short8*)&Wb[rh * 64 + (((ks * 4 + lh) ^ (rh & 7)) << 3)];
      }
    __builtin_amdgcn_s_setprio(1);
#pragma unroll
    for (int mi = 0; mi < 4; ++mi)
#pragma unroll
      for (int ni = 0; ni < 2; ++ni)
#pragma unroll
        for (int ks = 0; ks < 2; ++ks)
          acc[mi][2 + ni] = mfma_bf16(af[mi][ks], bf[ni][ks], acc[mi][2 + ni]);
    __builtin_amdgcn_s_setprio(0);
    __builtin_amdgcn_s_barrier();
    // ---- phase 2: A hi half-frags (B cols 32..63 kept)
#pragma unroll
    for (int mi = 0; mi < 4; ++mi)
#pragma unroll
      for (int ks = 0; ks < 2; ++ks) {
        int rh = (4 + mi) * 16 + l15;
        af[mi][ks] = *(const short8*)&Ab[rh * 64 + (((ks * 4 + lh) ^ (rh & 7)) << 3)];
      }
    __builtin_amdgcn_s_setprio(1);
#pragma unroll
    for (int mi = 0; mi < 4; ++mi)
#pragma unroll
      for (int ni = 0; ni < 2; ++ni)
#pragma unroll
        for (int ks = 0; ks < 2; ++ks)
          acc[4 + mi][2 + ni] = mfma_bf16(af[mi][ks], bf[ni][ks], acc[4 + mi][2 + ni]);
    __builtin_amdgcn_s_setprio(0);
    __builtin_amdgcn_s_barrier();
    // ---- phase 3: B cols 0..31 again (A hi kept)
#pragma unroll
    for (int ni = 0; ni < 2; ++ni)
#pragma unroll
      for (int ks = 0; ks < 2; ++ks) {
        int rh = wrow + ni * 16 + l15;
        bf[ni][ks] = *(const short8*)&Wb[rh * 64 + (((ks * 4 + lh) ^ (rh & 7)) << 3)];
      }
    __builtin_amdgcn_s_setprio(1);
#pragma unroll
    for (int mi = 0; mi < 4; ++mi)
#pragma unroll
      for (int ni = 0; ni < 2; ++ni)
#pragma unroll
        for (int ks = 0; ks < 2; ++ks)
          acc[4 + mi][ni] = mfma_bf16(af[mi][ks], bf[ni][ks], acc[4 + mi][ni]);
    __builtin_amdgcn_s_setprio(0);

    // B2: all reads of buf[p] complete before next iter's issue overwrites it
    asm volatile("s_waitcnt lgkmcnt(0)" ::: "memory");
    __builtin_amdgcn_sched_barrier(0);
    __builtin_amdgcn_s_barrier();
    __builtin_amdgcn_sched_barrier(0);
  }

  // ---- epilogue
#pragma unroll
  for (int mi = 0; mi < 8; ++mi)
#pragma unroll
    for (int ni = 0; ni < 4; ++ni)
#pragma unroll
      for (int j = 0; j < 4; ++j) {
        int row = brow + wm * 128 + mi * 16 + lh * 4 + j;
        int col = bcol + wn * 64 + ni * 16 + l15;
        C[(size_t)row * N + col] = f2b(acc[mi][ni][j]);
      }
}

// ---------- GEMM (m97 structure): C[M,N] = A[M,K] * W[N,K]^T ----------
// Used for the WO projection (N=2048: 256^2 tiling would leave 50% of CUs idle).
template <bool OUTBF>
__global__ __launch_bounds__(256) void gemm_bt(const u16* __restrict__ A,
                                               const u16* __restrict__ W,
                                               void* __restrict__ Cout,
                                               int M, int N, int K) {
  __shared__ __align__(16) u16 As[128 * 32];
  __shared__ __align__(16) u16 Ws[128 * 32];
  const int tid = threadIdx.x, lane = tid & 63, wid = tid >> 6;
  const int wr = wid >> 1, wc = wid & 1;
  const int gx = gridDim.x;
  const int lin = blockIdx.y * gx + blockIdx.x;
  const int cpx = (gx * gridDim.y) >> 3;
  const int swz = (lin & 7) * cpx + (lin >> 3);
  const int brow = (swz / gx) * 128, bcol = (swz % gx) * 128;
  const int l15 = lane & 15, lh = lane >> 4;

  const int c0 = wid * 64 + lane;
  const int c1 = c0 + 256;
  const u16* Ag0 = A + (size_t)(brow + (c0 >> 2)) * K + ((c0 & 3) << 3);
  const u16* Ag1 = A + (size_t)(brow + (c1 >> 2)) * K + ((c1 & 3) << 3);
  const u16* Wg0 = W + (size_t)(bcol + (c0 >> 2)) * K + ((c0 & 3) << 3);
  const u16* Wg1 = W + (size_t)(bcol + (c1 >> 2)) * K + ((c1 & 3) << 3);
  u16* lA0 = &As[(wid * 64) * 8];
  u16* lA1 = &As[(wid * 64 + 256) * 8];
  u16* lW0 = &Ws[(wid * 64) * 8];
  u16* lW1 = &Ws[(wid * 64 + 256) * 8];

  f32x4 acc[4][4];
#pragma unroll
  for (int m = 0; m < 4; ++m)
#pragma unroll
    for (int n = 0; n < 4; ++n) acc[m][n] = (f32x4)0.0f;

  for (int k0 = 0; k0 < K; k0 += 32) {
    __syncthreads();
    gload_lds16(Ag0 + k0, lA0);
    gload_lds16(Ag1 + k0, lA1);
    gload_lds16(Wg0 + k0, lW0);
    gload_lds16(Wg1 + k0, lW1);
    __syncthreads();
    short8 af[4], bfr[4];
#pragma unroll
    for (int m = 0; m < 4; ++m)
      af[m] = *(const short8*)&As[(wr * 64 + m * 16 + l15) * 32 + (lh << 3)];
#pragma unroll
    for (int n = 0; n < 4; ++n)
      bfr[n] = *(const short8*)&Ws[(wc * 64 + n * 16 + l15) * 32 + (lh << 3)];
#pragma unroll
    for (int m = 0; m < 4; ++m)
#pragma unroll
      for (int n = 0; n < 4; ++n)
        acc[m][n] = mfma_bf16(af[m], bfr[n], acc[m][n]);
  }

#pragma unroll
  for (int m = 0; m < 4; ++m)
#pragma unroll
    for (int n = 0; n < 4; ++n)
#pragma unroll
      for (int j = 0; j < 4; ++j) {
        int row = brow + wr * 64 + m * 16 + lh * 4 + j;
        int col = bcol + wc * 64 + n * 16 + l15;
        if (OUTBF)
          ((u16*)Cout)[(size_t)row * N + col] = f2b(acc[m][n][j]);
        else
          ((float*)Cout)[(size_t)row * N + col] = acc[m][n][j];
      }
}

// ---------- fused causal GQA flash attention (R7, unchanged) ----------
#define QBLK 128
#define KVBLK 128

static __device__ __forceinline__ void attn_tile(
    const short8* qa, f32x4* o, f32x4& ol, float* mrow,
    int qrow0, int kv0,
    const u16* Ks, const unsigned* Vt32, u16* myP,
    int l15, int lh, short8 ones8) {
  if (kv0 > qrow0 + 15) return;   // fully masked for this wave

  f32x4 s[4];
#pragma unroll
  for (int nt = 0; nt < 4; ++nt) s[nt] = (f32x4)0.0f;
  __builtin_amdgcn_s_setprio(1);
#pragma unroll
  for (int nt = 0; nt < 4; ++nt)
#pragma unroll
    for (int kk = 0; kk < 4; ++kk) {
      short8 kb = *(const short8*)&Ks[(nt * 16 + l15) * 136 + kk * 32 + (lh << 3)];
      s[nt] = mfma_bf16(qa[kk], kb, s[nt]);
    }
  __builtin_amdgcn_s_setprio(0);

  const int qg = qrow0 + lh * 4;
#pragma unroll
  for (int j = 0; j < 4; ++j)
#pragma unroll
    for (int nt = 0; nt < 4; ++nt)
      if (kv0 + nt * 16 + l15 > qg + j) s[nt][j] = -1e30f;

  float mt[4];
#pragma unroll
  for (int j = 0; j < 4; ++j)
    mt[j] = fmaxf(fmaxf(s[0][j], s[1][j]), fmaxf(s[2][j], s[3][j]));
#pragma unroll
  for (int d = 1; d <= 8; d <<= 1)
#pragma unroll
    for (int j = 0; j < 4; ++j) mt[j] = fmaxf(mt[j], __shfl_xor(mt[j], d));

  // defer-max (T13): rescale only when max grew by > 8
  float gmax = mt[0] - mrow[0];
#pragma unroll
  for (int j = 1; j < 4; ++j) gmax = fmaxf(gmax, mt[j] - mrow[j]);
  if (!__all(gmax <= 8.0f)) {
#pragma unroll
    for (int j = 0; j < 4; ++j) {
      float mn = fmaxf(mrow[j], mt[j]);
      float a = __expf(mrow[j] - mn);
      mrow[j] = mn;
      ol[j] *= a;
#pragma unroll
      for (int n = 0; n < 8; ++n) o[n][j] *= a;
    }
  }

  f32x4 p[4];
#pragma unroll
  for (int nt = 0; nt < 4; ++nt)
#pragma unroll
    for (int j = 0; j < 4; ++j) p[nt][j] = __expf(s[nt][j] - mrow[j]);

  // P -> per-wave LDS (transpose to A-frag layout)
#pragma unroll
  for (int nt = 0; nt < 4; ++nt)
#pragma unroll
    for (int j = 0; j < 4; ++j)
      myP[(lh * 4 + j) * 72 + nt * 16 + l15] = f2b(p[nt][j]);

  // PV (+ row-sum via ones-MFMA instead of shuffles)
  __builtin_amdgcn_s_setprio(1);
#pragma unroll
  for (int c = 0; c < 2; ++c) {
    short8 pa = *(const short8*)&myP[l15 * 72 + c * 32 + (lh << 3)];
    ol = mfma_bf16(pa, ones8, ol);
#pragma unroll
    for (int nt2 = 0; nt2 < 8; ++nt2) {
      int d = nt2 * 16 + l15;
      int byteoff = (d * 144 + (c * 32 + lh * 8) * 2) ^ (((d >> 3) & 7) << 4);
      short8 vb = *(const short8*)((const char*)Vt32 + byteoff);
      o[nt2] = mfma_bf16(pa, vb, o[nt2]);
    }
  }
  __builtin_amdgcn_s_setprio(0);
}

__global__ __launch_bounds__(512) void attn_kernel(const u16* __restrict__ QKV,
                                                   const float* __restrict__ rope,
                                                   u16* __restrict__ Y) {
  __shared__ __align__(16) u16 Ks[2][64 * 136];        // 2 x 17408 B
  __shared__ __align__(16) unsigned Vt32[2][128 * 36]; // 2 x 18432 B
  __shared__ __align__(16) u16 Ps[8][16 * 72];         // 18432 B

  const int tid = threadIdx.x, lane = tid & 63, wid = tid >> 6;
  const int l15 = lane & 15, lh = lane >> 4;
  const int bid = blockIdx.x;
  const int qpair = bid & 7;
  const int h = (bid >> 3) & 15;
  const int b = bid >> 7;
  const int kvh = h >> 2;
  const int qtA = qpair, qtB = 15 - qpair;
  const int rowA = qtA * QBLK + wid * 16;
  const int rowB = qtB * QBLK + wid * 16;

  const u16* Kb_ = QKV + (size_t)b * TT * QSTR + DD + kvh * HD;  // K cols
  const u16* Vb_ = Kb_ + NKVH * HD;                              // V cols

  short8 ones8;
#pragma unroll
  for (int e = 0; e < 8; ++e) ones8[e] = (short)0x3F80;  // bf16 1.0

  short8 qaA[4], qaB[4];
  {
    const u16* qA = QKV + (size_t)(b * TT + rowA + l15) * QSTR + h * HD + (lh << 3);
    const u16* qB = QKV + (size_t)(b * TT + rowB + l15) * QSTR + h * HD + (lh << 3);
#pragma unroll
    for (int kk = 0; kk < 4; ++kk) {
      qaA[kk] = *(const short8*)(qA + kk * 32);
      qaB[kk] = *(const short8*)(qB + kk * 32);
    }
  }
  // ---- fused Q-RoPE + softmax scale (pair (i, i+64) = qa[kk] / qa[kk+2])
  {
    const float* rpA = rope + (size_t)(rowA + l15) * 128;
    const float* rpB = rope + (size_t)(rowB + l15) * 128;
#pragma unroll
    for (int kk = 0; kk < 2; ++kk)
#pragma unroll
      for (int e = 0; e < 8; ++e) {
        const int i2 = 2 * (kk * 32 + (lh << 3) + e);
        float c = rpA[i2], s = rpA[i2 + 1];
        float x1 = b2f((u16)qaA[kk][e]), x2 = b2f((u16)qaA[kk + 2][e]);
        qaA[kk][e]     = (short)f2b(QSCALE * (x1 * c - x2 * s));
        qaA[kk + 2][e] = (short)f2b(QSCALE * (x1 * s + x2 * c));
        float cb = rpB[i2], sb = rpB[i2 + 1];
        float y1 = b2f((u16)qaB[kk][e]), y2 = b2f((u16)qaB[kk + 2][e]);
        qaB[kk][e]     = (short)f2b(QSCALE * (y1 * cb - y2 * sb));
        qaB[kk + 2][e] = (short)f2b(QSCALE * (y1 * sb + y2 * cb));
      }
  }

  f32x4 oA[8], oB[8];
  f32x4 olA = (f32x4)0.0f, olB = (f32x4)0.0f;
  float mA[4], mB[4];
#pragma unroll
  for (int n = 0; n < 8; ++n) { oA[n] = (f32x4)0.0f; oB[n] = (f32x4)0.0f; }
#pragma unroll
  for (int j = 0; j < 4; ++j) { mA[j] = -1e30f; mB[j] = -1e30f; }

  const int kvend = (qtB + 1) * QBLK;   // multiple of 128

  // staging registers (T14: issue early, write late); 128 KV rows per pass
  short8 kreg[4], vreg[4];
  const int srow = tid >> 4;           // 0..31
  const int sc8 = (tid & 15) << 3;

  auto issue = [&](int kv0) {
    kreg[0] = *(const short8*)&Kb_[(size_t)(kv0 + srow) * QSTR + sc8];
    kreg[1] = *(const short8*)&Kb_[(size_t)(kv0 + 32 + srow) * QSTR + sc8];
    kreg[2] = *(const short8*)&Kb_[(size_t)(kv0 + 64 + srow) * QSTR + sc8];
    kreg[3] = *(const short8*)&Kb_[(size_t)(kv0 + 96 + srow) * QSTR + sc8];
    vreg[0] = *(const short8*)&Vb_[(size_t)(kv0 + 2 * srow) * QSTR + sc8];
    vreg[1] = *(const short8*)&Vb_[(size_t)(kv0 + 2 * srow + 1) * QSTR + sc8];
    vreg[2] = *(const short8*)&Vb_[(size_t)(kv0 + 64 + 2 * srow) * QSTR + sc8];
    vreg[3] = *(const short8*)&Vb_[(size_t)(kv0 + 64 + 2 * srow + 1) * QSTR + sc8];
  };

  issue(0);
  for (int kv0 = 0; kv0 < kvend; kv0 += KVBLK) {
    __syncthreads();   // previous tile's LDS reads done
    *(short8*)&Ks[0][srow * 136 + sc8] = kreg[0];
    *(short8*)&Ks[0][(srow + 32) * 136 + sc8] = kreg[1];
    *(short8*)&Ks[1][srow * 136 + sc8] = kreg[2];
    *(short8*)&Ks[1][(srow + 32) * 136 + sc8] = kreg[3];
#pragma unroll
    for (int e = 0; e < 8; ++e) {
      int d = sc8 + e;
      unsigned pk0 = (unsigned)(u16)vreg[0][e] | ((unsigned)(u16)vreg[1][e] << 16);
      unsigned pk1 = (unsigned)(u16)vreg[2][e] | ((unsigned)(u16)vreg[3][e] << 16);
      int byteoff = (d * 144 + 4 * srow) ^ (((d >> 3) & 7) << 4);
      *(unsigned*)((char*)&Vt32[0][0] + byteoff) = pk0;
      *(unsigned*)((char*)&Vt32[1][0] + byteoff) = pk1;
    }
    __syncthreads();   // staged tile visible
    if (kv0 + KVBLK < kvend) issue(kv0 + KVBLK);  // overlap next loads with compute

    attn_tile(qaA, oA, olA, mA, rowA, kv0,      &Ks[0][0], &Vt32[0][0], &Ps[wid][0], l15, lh, ones8);
    attn_tile(qaA, oA, olA, mA, rowA, kv0 + 64, &Ks[1][0], &Vt32[1][0], &Ps[wid][0], l15, lh, ones8);
    attn_tile(qaB, oB, olB, mB, rowB, kv0,      &Ks[0][0], &Vt32[0][0], &Ps[wid][0], l15, lh, ones8);
    attn_tile(qaB, oB, olB, mB, rowB, kv0 + 64, &Ks[1][0], &Vt32[1][0], &Ps[wid][0], l15, lh, ones8);
  }

  f32x4 invA, invB;
#pragma unroll
  for (int j = 0; j < 4; ++j) {
    invA[j] = __builtin_amdgcn_rcpf(olA[j]);
    invB[j] = __builtin_amdgcn_rcpf(olB[j]);
  }
#pragma unroll
  for (int nt = 0; nt < 8; ++nt)
#pragma unroll
    for (int j = 0; j < 4; ++j) {
      Y[(size_t)(b * TT + rowA + lh * 4 + j) * DD + h * HD + nt * 16 + l15] =
          f2b(oA[nt][j] * invA[j]);
      Y[(size_t)(b * TT + rowB + lh * 4 + j) * DD + h * HD + nt * 16 + l15] =
          f2b(oB[nt][j] * invB[j]);
    }
}

// ---------- launcher ----------
extern "C" void kernel_launch(void* const* d_in, const int* in_sizes, int n_in,
                              void* d_out, int out_size, void* d_ws, size_t ws_size,
                              hipStream_t stream) {
  const float* x    = (const float*)d_in[0];
  const float* rope = (const float*)d_in[1];
  const float* wq   = (const float*)d_in[2];
  const float* wk   = (const float*)d_in[3];
  const float* wv   = (const float*)d_in[4];
  const float* wo   = (const float*)d_in[5];
  float* out = (float*)d_out;

  char* ws = (char*)d_ws;
  u16* xb    = (u16*)ws; ws += (size_t)MM * DD * 2;        // 16.8 MB
  u16* wqkvb = (u16*)ws; ws += (size_t)QSTR * DD * 2;      // 12.6 MB (wq|wk|wv rows)
  u16* wob   = (u16*)ws; ws += (size_t)DD * DD * 2;        //  8.4 MB
  u16* QKVb  = (u16*)ws; ws += (size_t)MM * QSTR * 2;      // 25.2 MB
  u16* Yb    = (u16*)ws;                                   // 16.8 MB

  // 1) fused converts: x, wq, wk, wv, wo in ONE launch
  cvt_all<<<2048, 256, 0, stream>>>(x, wq, wk, wv, wo, xb, wqkvb, wob);

  // 2) fused QKV projection: 256^2 8-phase-style GEMM (192 blocks)
  gemm_qkv<<<dim3(QSTR / 256, MM / 256), 512, 0, stream>>>(xb, wqkvb, QKVb, MM, QSTR, DD);

  // 3) RoPE on K only (Q-rope fused into attention)
  rope_k<<<(MM * NKVH * 64) / 256, 256, 0, stream>>>(QKVb + DD, rope);

  // 4) attention (R7 structure, unchanged)
  attn_kernel<<<BB * NH * (TT / QBLK / 2), 512, 0, stream>>>(QKVb, rope, Yb);

  // 5) output projection (fp32 out, m97 structure + T1)
  gemm_bt<false><<<dim3(DD / 128, MM / 128), 256, 0, stream>>>(Yb, wob, out, MM, DD, DD);
}

// Round 9
// 217.692 us; speedup vs baseline: 1.0427x; 1.0427x over previous
//
#include <hip/hip_runtime.h>

// ---------- types & helpers ----------
typedef unsigned short u16;
typedef float   f32x4  __attribute__((ext_vector_type(4)));
typedef short   short8 __attribute__((ext_vector_type(8)));
typedef __bf16  bf16x8 __attribute__((ext_vector_type(8)));
typedef float   float4v __attribute__((ext_vector_type(4)));
typedef unsigned short u16x4 __attribute__((ext_vector_type(4)));

// native HW bf16 convert (RNE) — do not hand-roll (T12/m240)
static __device__ __forceinline__ u16 f2b(float f) {
  return __builtin_bit_cast(u16, (__bf16)f);
}
static __device__ __forceinline__ float b2f(u16 h) {
  union { unsigned u; float f; } v; v.u = ((unsigned)h) << 16;
  return v.f;
}
static __device__ __forceinline__ f32x4 mfma_bf16(short8 a, short8 b, f32x4 c) {
  return __builtin_amdgcn_mfma_f32_16x16x32_bf16(
      __builtin_bit_cast(bf16x8, a), __builtin_bit_cast(bf16x8, b), c, 0, 0, 0);
}
// async global->LDS, 16B per lane; lds ptr must be wave-uniform base (HW adds lane*16)
static __device__ __forceinline__ void gload_lds16(const u16* g, u16* l) {
  __builtin_amdgcn_global_load_lds(
      (const __attribute__((address_space(1))) unsigned int*)g,
      (__attribute__((address_space(3))) unsigned int*)l, 16, 0, 0);
}

// ---------- problem constants ----------
#define BB 2
#define TT 2048
#define DD 2048
#define NH 16
#define NKVH 4
#define HD 128
#define MM (BB * TT)          // 4096 rows
#define QSTR 3072             // fused QKV projection row: [Q(2048) | K(512) | V(512)]
#define QSCALE 0.08838834764831845f

// ---------- fused fp32 -> bf16 convert (all 5 tensors, 1 launch) ----------
#define N4_X   ((MM * DD) / 4)
#define N4_WQ  ((DD * DD) / 4)
#define N4_WKV ((NKVH * HD * DD) / 4)
#define N4_WO  ((DD * DD) / 4)
#define N4_TOT (N4_X + N4_WQ + 2 * N4_WKV + N4_WO)

__global__ __launch_bounds__(256) void cvt_all(const float* __restrict__ x,
                                               const float* __restrict__ wq,
                                               const float* __restrict__ wk,
                                               const float* __restrict__ wv,
                                               const float* __restrict__ wo,
                                               u16* __restrict__ xb,
                                               u16* __restrict__ wqkvb,
                                               u16* __restrict__ wob) {
  int stride = gridDim.x * blockDim.x;
  for (int i = blockIdx.x * blockDim.x + threadIdx.x; i < N4_TOT; i += stride) {
    const float4v* src;
    u16x4* dst;
    int off;
    if (i < N4_X) {
      src = (const float4v*)x; dst = (u16x4*)xb; off = i;
    } else if (i < N4_X + N4_WQ) {
      src = (const float4v*)wq; dst = (u16x4*)wqkvb; off = i - N4_X;
    } else if (i < N4_X + N4_WQ + N4_WKV) {
      src = (const float4v*)wk; dst = (u16x4*)wqkvb + N4_WQ; off = i - (N4_X + N4_WQ);
    } else if (i < N4_X + N4_WQ + 2 * N4_WKV) {
      src = (const float4v*)wv; dst = (u16x4*)wqkvb + N4_WQ + N4_WKV;
      off = i - (N4_X + N4_WQ + N4_WKV);
    } else {
      src = (const float4v*)wo; dst = (u16x4*)wob; off = i - (N4_X + N4_WQ + 2 * N4_WKV);
    }
    float4v v = src[off];
    u16x4 o;
    o[0] = f2b(v[0]); o[1] = f2b(v[1]); o[2] = f2b(v[2]); o[3] = f2b(v[3]);
    dst[off] = o;
  }
}

// ---------- RoPE on K only (Q-rope is fused into the attention prologue) ----------
__global__ __launch_bounds__(256) void rope_k(u16* __restrict__ K,
                                              const float* __restrict__ rope) {
  int idx = blockIdx.x * 256 + threadIdx.x;
  int i  = idx & 63;
  int h  = (idx >> 6) & (NKVH - 1);
  int bt = idx >> 8;
  int t  = bt & (TT - 1);
  size_t base = (size_t)bt * QSTR + h * HD + i;
  float x1 = b2f(K[base]);
  float x2 = b2f(K[base + 64]);
  float c = rope[t * 128 + 2 * i];
  float s = rope[t * 128 + 2 * i + 1];
  K[base]      = f2b(x1 * c - x2 * s);
  K[base + 64] = f2b(x1 * s + x2 * c);
}

// ---------- 8-phase-style 256x256 GEMM (QKV projection) ----------
__global__ __launch_bounds__(512, 2) void gemm_qkv(const u16* __restrict__ A,
                                                   const u16* __restrict__ W,
                                                   u16* __restrict__ C,
                                                   int M, int N, int K) {
  __shared__ __align__(16) u16 As[2][2][128 * 64];  // [buf][half][r*64+swz]
  __shared__ __align__(16) u16 Ws[2][2][128 * 64];

  const int tid = threadIdx.x, lane = tid & 63, wid = tid >> 6;
  const int wm = wid >> 2, wn = wid & 3;
  const int l15 = lane & 15, lh = lane >> 4;

  // T1 bijective XCD swizzle (nwg = 192, %8 == 0)
  const int nwg = gridDim.x * gridDim.y;
  const int lin = blockIdx.y * gridDim.x + blockIdx.x;
  const int swz = (lin & 7) * (nwg >> 3) + (lin >> 3);
  const int brow = (swz / gridDim.x) * 256, bcol = (swz % gridDim.x) * 256;

  const int srp = wid * 8 + (lane >> 3);
  const int gsw = ((lane & 7) ^ (lane >> 3)) << 3;
  const u16* sa[2][2];
  const u16* sw[2][2];
#pragma unroll
  for (int mh = 0; mh < 2; ++mh)
#pragma unroll
    for (int i = 0; i < 2; ++i) {
      sa[mh][i] = A + (size_t)(brow + mh * 128 + i * 64 + srp) * K + gsw;
      sw[mh][i] = W + (size_t)(bcol + mh * 128 + i * 64 + srp) * K + gsw;
    }

  f32x4 acc[8][4];
#pragma unroll
  for (int mi = 0; mi < 8; ++mi)
#pragma unroll
    for (int ni = 0; ni < 4; ++ni) acc[mi][ni] = (f32x4)0.0f;

  const int nk = K >> 6;  // 64-wide K tiles

  auto issue = [&](int t, int p) {
#pragma unroll
    for (int mh = 0; mh < 2; ++mh)
#pragma unroll
      for (int i = 0; i < 2; ++i) {
        gload_lds16(sa[mh][i] + t * 64, &As[p][mh][i * 4096 + wid * 512]);
        gload_lds16(sw[mh][i] + t * 64, &Ws[p][mh][i * 4096 + wid * 512]);
      }
  };

  issue(0, 0);
  for (int t = 0; t < nk; ++t) {
    const int p = t & 1;
    if (t + 1 < nk) {
      issue(t + 1, p ^ 1);  // next tile: 8 loads stay in flight across compute
      asm volatile("s_waitcnt vmcnt(8)" ::: "memory");  // tile t's 8 landed
    } else {
      asm volatile("s_waitcnt vmcnt(0)" ::: "memory");
    }
    __builtin_amdgcn_sched_barrier(0);
    __builtin_amdgcn_s_barrier();   // B1: all waves' tile-t stages visible
    __builtin_amdgcn_sched_barrier(0);

    const u16* Ab = &As[p][wm][0];
    const u16* Wb = &Ws[p][wn >> 1][0];
    const int wrow = (wn & 1) * 64;

    short8 af[4][2], bf[2][2];
    // ---- phase 0: A lo half-frags + B cols 0..31
#pragma unroll
    for (int mi = 0; mi < 4; ++mi)
#pragma unroll
      for (int ks = 0; ks < 2; ++ks) {
        int rh = mi * 16 + l15;
        af[mi][ks] = *(const short8*)&Ab[rh * 64 + (((ks * 4 + lh) ^ (rh & 7)) << 3)];
      }
#pragma unroll
    for (int ni = 0; ni < 2; ++ni)
#pragma unroll
      for (int ks = 0; ks < 2; ++ks) {
        int rh = wrow + ni * 16 + l15;
        bf[ni][ks] = *(const short8*)&Wb[rh * 64 + (((ks * 4 + lh) ^ (rh & 7)) << 3)];
      }
    __builtin_amdgcn_s_setprio(1);
#pragma unroll
    for (int mi = 0; mi < 4; ++mi)
#pragma unroll
      for (int ni = 0; ni < 2; ++ni)
#pragma unroll
        for (int ks = 0; ks < 2; ++ks)
          acc[mi][ni] = mfma_bf16(af[mi][ks], bf[ni][ks], acc[mi][ni]);
    __builtin_amdgcn_s_setprio(0);
    __builtin_amdgcn_s_barrier();
    // ---- phase 1: B cols 32..63 (A kept)
#pragma unroll
    for (int ni = 0; ni < 2; ++ni)
#pragma unroll
      for (int ks = 0; ks < 2; ++ks) {
        int rh = wrow + (2 + ni) * 16 + l15;
        bf[ni][ks] = *(const short8*)&Wb[rh * 64 + (((ks * 4 + lh) ^ (rh & 7)) << 3)];
      }
    __builtin_amdgcn_s_setprio(1);
#pragma unroll
    for (int mi = 0; mi < 4; ++mi)
#pragma unroll
      for (int ni = 0; ni < 2; ++ni)
#pragma unroll
        for (int ks = 0; ks < 2; ++ks)
          acc[mi][2 + ni] = mfma_bf16(af[mi][ks], bf[ni][ks], acc[mi][2 + ni]);
    __builtin_amdgcn_s_setprio(0);
    __builtin_amdgcn_s_barrier();
    // ---- phase 2: A hi half-frags (B cols 32..63 kept)
#pragma unroll
    for (int mi = 0; mi < 4; ++mi)
#pragma unroll
      for (int ks = 0; ks < 2; ++ks) {
        int rh = (4 + mi) * 16 + l15;
        af[mi][ks] = *(const short8*)&Ab[rh * 64 + (((ks * 4 + lh) ^ (rh & 7)) << 3)];
      }
    __builtin_amdgcn_s_setprio(1);
#pragma unroll
    for (int mi = 0; mi < 4; ++mi)
#pragma unroll
      for (int ni = 0; ni < 2; ++ni)
#pragma unroll
        for (int ks = 0; ks < 2; ++ks)
          acc[4 + mi][2 + ni] = mfma_bf16(af[mi][ks], bf[ni][ks], acc[4 + mi][2 + ni]);
    __builtin_amdgcn_s_setprio(0);
    __builtin_amdgcn_s_barrier();
    // ---- phase 3: B cols 0..31 again (A hi kept)
#pragma unroll
    for (int ni = 0; ni < 2; ++ni)
#pragma unroll
      for (int ks = 0; ks < 2; ++ks) {
        int rh = wrow + ni * 16 + l15;
        bf[ni][ks] = *(const short8*)&Wb[rh * 64 + (((ks * 4 + lh) ^ (rh & 7)) << 3)];
      }
    __builtin_amdgcn_s_setprio(1);
#pragma unroll
    for (int mi = 0; mi < 4; ++mi)
#pragma unroll
      for (int ni = 0; ni < 2; ++ni)
#pragma unroll
        for (int ks = 0; ks < 2; ++ks)
          acc[4 + mi][ni] = mfma_bf16(af[mi][ks], bf[ni][ks], acc[4 + mi][ni]);
    __builtin_amdgcn_s_setprio(0);

    // B2: all reads of buf[p] complete before next iter's issue overwrites it
    asm volatile("s_waitcnt lgkmcnt(0)" ::: "memory");
    __builtin_amdgcn_sched_barrier(0);
    __builtin_amdgcn_s_barrier();
    __builtin_amdgcn_sched_barrier(0);
  }

  // ---- epilogue
#pragma unroll
  for (int mi = 0; mi < 8; ++mi)
#pragma unroll
    for (int ni = 0; ni < 4; ++ni)
#pragma unroll
      for (int j = 0; j < 4; ++j) {
        int row = brow + wm * 128 + mi * 16 + lh * 4 + j;
        int col = bcol + wn * 64 + ni * 16 + l15;
        C[(size_t)row * N + col] = f2b(acc[mi][ni][j]);
      }
}

// ---------- GEMM (m97 structure): C[M,N] = A[M,K] * W[N,K]^T ----------
// Used for the WO projection (N=2048: 256^2 tiling would leave 50% of CUs idle).
template <bool OUTBF>
__global__ __launch_bounds__(256) void gemm_bt(const u16* __restrict__ A,
                                               const u16* __restrict__ W,
                                               void* __restrict__ Cout,
                                               int M, int N, int K) {
  __shared__ __align__(16) u16 As[128 * 32];
  __shared__ __align__(16) u16 Ws[128 * 32];
  const int tid = threadIdx.x, lane = tid & 63, wid = tid >> 6;
  const int wr = wid >> 1, wc = wid & 1;
  const int gx = gridDim.x;
  const int lin = blockIdx.y * gx + blockIdx.x;
  const int cpx = (gx * gridDim.y) >> 3;
  const int swz = (lin & 7) * cpx + (lin >> 3);
  const int brow = (swz / gx) * 128, bcol = (swz % gx) * 128;
  const int l15 = lane & 15, lh = lane >> 4;

  const int c0 = wid * 64 + lane;
  const int c1 = c0 + 256;
  const u16* Ag0 = A + (size_t)(brow + (c0 >> 2)) * K + ((c0 & 3) << 3);
  const u16* Ag1 = A + (size_t)(brow + (c1 >> 2)) * K + ((c1 & 3) << 3);
  const u16* Wg0 = W + (size_t)(bcol + (c0 >> 2)) * K + ((c0 & 3) << 3);
  const u16* Wg1 = W + (size_t)(bcol + (c1 >> 2)) * K + ((c1 & 3) << 3);
  u16* lA0 = &As[(wid * 64) * 8];
  u16* lA1 = &As[(wid * 64 + 256) * 8];
  u16* lW0 = &Ws[(wid * 64) * 8];
  u16* lW1 = &Ws[(wid * 64 + 256) * 8];

  f32x4 acc[4][4];
#pragma unroll
  for (int m = 0; m < 4; ++m)
#pragma unroll
    for (int n = 0; n < 4; ++n) acc[m][n] = (f32x4)0.0f;

  for (int k0 = 0; k0 < K; k0 += 32) {
    __syncthreads();
    gload_lds16(Ag0 + k0, lA0);
    gload_lds16(Ag1 + k0, lA1);
    gload_lds16(Wg0 + k0, lW0);
    gload_lds16(Wg1 + k0, lW1);
    __syncthreads();
    short8 af[4], bfr[4];
#pragma unroll
    for (int m = 0; m < 4; ++m)
      af[m] = *(const short8*)&As[(wr * 64 + m * 16 + l15) * 32 + (lh << 3)];
#pragma unroll
    for (int n = 0; n < 4; ++n)
      bfr[n] = *(const short8*)&Ws[(wc * 64 + n * 16 + l15) * 32 + (lh << 3)];
#pragma unroll
    for (int m = 0; m < 4; ++m)
#pragma unroll
      for (int n = 0; n < 4; ++n)
        acc[m][n] = mfma_bf16(af[m], bfr[n], acc[m][n]);
  }

#pragma unroll
  for (int m = 0; m < 4; ++m)
#pragma unroll
    for (int n = 0; n < 4; ++n)
#pragma unroll
      for (int j = 0; j < 4; ++j) {
        int row = brow + wr * 64 + m * 16 + lh * 4 + j;
        int col = bcol + wc * 64 + n * 16 + l15;
        if (OUTBF)
          ((u16*)Cout)[(size_t)row * N + col] = f2b(acc[m][n][j]);
        else
          ((float*)Cout)[(size_t)row * N + col] = acc[m][n][j];
      }
}

// ---------- fused causal GQA flash attention ----------
// R7 shell (256 blocks x 8 waves, paired q-tiles, T14 staging, KVBLK=128).
// NEW: swapped QK^T — st = mfma(K, Q) (A/B frags have identical lane
// layouts, so same loads). Lane now holds S[kv=kv0+nt*16+lh*4+j][q=l15]:
//   * row-max is in-lane (15 fmax + 2 shfl_xor vs 28 fmax + 16 shfl)
//   * row-sum is in-lane adds -> ones-MFMA dropped (l scalar, lh-reduced
//     once in the epilogue)
//   * P stored as 8 pair-packed ds_write_b32 at elem l15*72+kv (vs 16
//     scalar b16); PV read pattern byte-identical to the verified one.
#define QBLK 128
#define KVBLK 128

static __device__ __forceinline__ void attn_tile(
    const short8* qa, f32x4* o, float& l, float& m,
    int qrow0, int kv0,
    const u16* Ks, const unsigned* Vt32, u16* myP,
    int l15, int lh) {
  if (kv0 > qrow0 + 15) return;   // fully masked for this wave

  // ---- swapped QK^T: st[nt][j] = S[kv = kv0+nt*16+lh*4+j][q = qrow0+l15]
  f32x4 st[4];
#pragma unroll
  for (int nt = 0; nt < 4; ++nt) st[nt] = (f32x4)0.0f;
  __builtin_amdgcn_s_setprio(1);
#pragma unroll
  for (int nt = 0; nt < 4; ++nt) {
    const u16* krow = &Ks[(nt * 16 + l15) * 136 + (lh << 3)];
#pragma unroll
    for (int kk = 0; kk < 4; ++kk) {
      short8 kb = *(const short8*)(krow + kk * 32);
      st[nt] = mfma_bf16(kb, qa[kk], st[nt]);
    }
  }
  __builtin_amdgcn_s_setprio(0);

  // ---- causal mask: kv > q  <=>  (kv0 + lh*4 - qrow0 - l15) + nt*16 + j > 0
  const int kvq = kv0 + lh * 4 - qrow0 - l15;
#pragma unroll
  for (int nt = 0; nt < 4; ++nt)
#pragma unroll
    for (int j = 0; j < 4; ++j)
      if (kvq + nt * 16 + j > 0) st[nt][j] = -1e30f;

  // ---- in-lane row max (q = l15), then reduce across the 4 lh groups
  float mt = st[0][0];
#pragma unroll
  for (int nt = 0; nt < 4; ++nt)
#pragma unroll
    for (int j = 0; j < 4; ++j) mt = fmaxf(mt, st[nt][j]);
  mt = fmaxf(mt, __shfl_xor(mt, 16));
  mt = fmaxf(mt, __shfl_xor(mt, 32));

  // ---- defer-max (T13): rescale only when max grew by > 8
  if (!__all(mt - m <= 8.0f)) {
    float mn = fmaxf(m, mt);
    float a = __expf(m - mn);
    m = mn;
    l *= a;
    float aj[4];
#pragma unroll
    for (int j = 0; j < 4; ++j) aj[j] = __shfl(a, lh * 4 + j);
#pragma unroll
    for (int n = 0; n < 8; ++n)
#pragma unroll
      for (int j = 0; j < 4; ++j) o[n][j] *= aj[j];
  }

  // ---- P = exp(S - m); row-sum accumulated in-lane (partial over this lh)
  f32x4 p[4];
  float ps = 0.0f;
#pragma unroll
  for (int nt = 0; nt < 4; ++nt) {
#pragma unroll
    for (int j = 0; j < 4; ++j) p[nt][j] = __expf(st[nt][j] - m);
    ps += (p[nt][0] + p[nt][1]) + (p[nt][2] + p[nt][3]);
  }
  l += ps;

  // ---- P -> per-wave LDS, pair-packed b32 at elem l15*72 + kv
  unsigned* P32 = (unsigned*)myP;
  const int pb = l15 * 36 + lh * 2;
#pragma unroll
  for (int nt = 0; nt < 4; ++nt)
#pragma unroll
    for (int jj = 0; jj < 2; ++jj)
      P32[pb + nt * 8 + jj] =
          (unsigned)f2b(p[nt][2 * jj]) | ((unsigned)f2b(p[nt][2 * jj + 1]) << 16);

  // ---- PV (read pattern unchanged from verified kernel)
  __builtin_amdgcn_s_setprio(1);
#pragma unroll
  for (int c = 0; c < 2; ++c) {
    short8 pa = *(const short8*)&myP[l15 * 72 + c * 32 + (lh << 3)];
#pragma unroll
    for (int nt2 = 0; nt2 < 8; ++nt2) {
      int d = nt2 * 16 + l15;
      int byteoff = (d * 144 + (c * 32 + lh * 8) * 2) ^ (((d >> 3) & 7) << 4);
      short8 vb = *(const short8*)((const char*)Vt32 + byteoff);
      o[nt2] = mfma_bf16(pa, vb, o[nt2]);
    }
  }
  __builtin_amdgcn_s_setprio(0);
}

__global__ __launch_bounds__(512) void attn_kernel(const u16* __restrict__ QKV,
                                                   const float* __restrict__ rope,
                                                   u16* __restrict__ Y) {
  __shared__ __align__(16) u16 Ks[2][64 * 136];        // 2 x 17408 B
  __shared__ __align__(16) unsigned Vt32[2][128 * 36]; // 2 x 18432 B
  __shared__ __align__(16) u16 Ps[8][16 * 72];         // 18432 B

  const int tid = threadIdx.x, lane = tid & 63, wid = tid >> 6;
  const int l15 = lane & 15, lh = lane >> 4;
  const int bid = blockIdx.x;
  const int qpair = bid & 7;
  const int h = (bid >> 3) & 15;
  const int b = bid >> 7;
  const int kvh = h >> 2;
  const int qtA = qpair, qtB = 15 - qpair;
  const int rowA = qtA * QBLK + wid * 16;
  const int rowB = qtB * QBLK + wid * 16;

  const u16* Kb_ = QKV + (size_t)b * TT * QSTR + DD + kvh * HD;  // K cols
  const u16* Vb_ = Kb_ + NKVH * HD;                              // V cols

  short8 qaA[4], qaB[4];
  {
    const u16* qA = QKV + (size_t)(b * TT + rowA + l15) * QSTR + h * HD + (lh << 3);
    const u16* qB = QKV + (size_t)(b * TT + rowB + l15) * QSTR + h * HD + (lh << 3);
#pragma unroll
    for (int kk = 0; kk < 4; ++kk) {
      qaA[kk] = *(const short8*)(qA + kk * 32);
      qaB[kk] = *(const short8*)(qB + kk * 32);
    }
  }
  // ---- fused Q-RoPE + softmax scale (pair (i, i+64) = qa[kk] / qa[kk+2])
  {
    const float* rpA = rope + (size_t)(rowA + l15) * 128;
    const float* rpB = rope + (size_t)(rowB + l15) * 128;
#pragma unroll
    for (int kk = 0; kk < 2; ++kk)
#pragma unroll
      for (int e = 0; e < 8; ++e) {
        const int i2 = 2 * (kk * 32 + (lh << 3) + e);
        float c = rpA[i2], s = rpA[i2 + 1];
        float x1 = b2f((u16)qaA[kk][e]), x2 = b2f((u16)qaA[kk + 2][e]);
        qaA[kk][e]     = (short)f2b(QSCALE * (x1 * c - x2 * s));
        qaA[kk + 2][e] = (short)f2b(QSCALE * (x1 * s + x2 * c));
        float cb = rpB[i2], sb = rpB[i2 + 1];
        float y1 = b2f((u16)qaB[kk][e]), y2 = b2f((u16)qaB[kk + 2][e]);
        qaB[kk][e]     = (short)f2b(QSCALE * (y1 * cb - y2 * sb));
        qaB[kk + 2][e] = (short)f2b(QSCALE * (y1 * sb + y2 * cb));
      }
  }

  f32x4 oA[8], oB[8];
  float lA = 0.0f, lB = 0.0f;
  float mA = -1e30f, mB = -1e30f;
#pragma unroll
  for (int n = 0; n < 8; ++n) { oA[n] = (f32x4)0.0f; oB[n] = (f32x4)0.0f; }

  const int kvend = (qtB + 1) * QBLK;   // multiple of 128

  // staging registers (T14: issue early, write late); 128 KV rows per pass
  short8 kreg[4], vreg[4];
  const int srow = tid >> 4;           // 0..31
  const int sc8 = (tid & 15) << 3;

  auto issue = [&](int kv0) {
    kreg[0] = *(const short8*)&Kb_[(size_t)(kv0 + srow) * QSTR + sc8];
    kreg[1] = *(const short8*)&Kb_[(size_t)(kv0 + 32 + srow) * QSTR + sc8];
    kreg[2] = *(const short8*)&Kb_[(size_t)(kv0 + 64 + srow) * QSTR + sc8];
    kreg[3] = *(const short8*)&Kb_[(size_t)(kv0 + 96 + srow) * QSTR + sc8];
    vreg[0] = *(const short8*)&Vb_[(size_t)(kv0 + 2 * srow) * QSTR + sc8];
    vreg[1] = *(const short8*)&Vb_[(size_t)(kv0 + 2 * srow + 1) * QSTR + sc8];
    vreg[2] = *(const short8*)&Vb_[(size_t)(kv0 + 64 + 2 * srow) * QSTR + sc8];
    vreg[3] = *(const short8*)&Vb_[(size_t)(kv0 + 64 + 2 * srow + 1) * QSTR + sc8];
  };

  issue(0);
  for (int kv0 = 0; kv0 < kvend; kv0 += KVBLK) {
    __syncthreads();   // previous tile's LDS reads done
    *(short8*)&Ks[0][srow * 136 + sc8] = kreg[0];
    *(short8*)&Ks[0][(srow + 32) * 136 + sc8] = kreg[1];
    *(short8*)&Ks[1][srow * 136 + sc8] = kreg[2];
    *(short8*)&Ks[1][(srow + 32) * 136 + sc8] = kreg[3];
#pragma unroll
    for (int e = 0; e < 8; ++e) {
      int d = sc8 + e;
      unsigned pk0 = (unsigned)(u16)vreg[0][e] | ((unsigned)(u16)vreg[1][e] << 16);
      unsigned pk1 = (unsigned)(u16)vreg[2][e] | ((unsigned)(u16)vreg[3][e] << 16);
      int byteoff = (d * 144 + 4 * srow) ^ (((d >> 3) & 7) << 4);
      *(unsigned*)((char*)&Vt32[0][0] + byteoff) = pk0;
      *(unsigned*)((char*)&Vt32[1][0] + byteoff) = pk1;
    }
    __syncthreads();   // staged tile visible
    if (kv0 + KVBLK < kvend) issue(kv0 + KVBLK);  // overlap next loads with compute

    attn_tile(qaA, oA, lA, mA, rowA, kv0,      &Ks[0][0], &Vt32[0][0], &Ps[wid][0], l15, lh);
    attn_tile(qaA, oA, lA, mA, rowA, kv0 + 64, &Ks[1][0], &Vt32[1][0], &Ps[wid][0], l15, lh);
    attn_tile(qaB, oB, lB, mB, rowB, kv0,      &Ks[0][0], &Vt32[0][0], &Ps[wid][0], l15, lh);
    attn_tile(qaB, oB, lB, mB, rowB, kv0 + 64, &Ks[1][0], &Vt32[1][0], &Ps[wid][0], l15, lh);
  }

  // ---- epilogue: total row-sums (reduce over lh), redistribute to q=lh*4+j
  lA += __shfl_xor(lA, 16); lA += __shfl_xor(lA, 32);
  lB += __shfl_xor(lB, 16); lB += __shfl_xor(lB, 32);
  f32x4 invA, invB;
#pragma unroll
  for (int j = 0; j < 4; ++j) {
    invA[j] = __builtin_amdgcn_rcpf(__shfl(lA, lh * 4 + j));
    invB[j] = __builtin_amdgcn_rcpf(__shfl(lB, lh * 4 + j));
  }
#pragma unroll
  for (int nt = 0; nt < 8; ++nt)
#pragma unroll
    for (int j = 0; j < 4; ++j) {
      Y[(size_t)(b * TT + rowA + lh * 4 + j) * DD + h * HD + nt * 16 + l15] =
          f2b(oA[nt][j] * invA[j]);
      Y[(size_t)(b * TT + rowB + lh * 4 + j) * DD + h * HD + nt * 16 + l15] =
          f2b(oB[nt][j] * invB[j]);
    }
}

// ---------- launcher ----------
extern "C" void kernel_launch(void* const* d_in, const int* in_sizes, int n_in,
                              void* d_out, int out_size, void* d_ws, size_t ws_size,
                              hipStream_t stream) {
  const float* x    = (const float*)d_in[0];
  const float* rope = (const float*)d_in[1];
  const float* wq   = (const float*)d_in[2];
  const float* wk   = (const float*)d_in[3];
  const float* wv   = (const float*)d_in[4];
  const float* wo   = (const float*)d_in[5];
  float* out = (float*)d_out;

  char* ws = (char*)d_ws;
  u16* xb    = (u16*)ws; ws += (size_t)MM * DD * 2;        // 16.8 MB
  u16* wqkvb = (u16*)ws; ws += (size_t)QSTR * DD * 2;      // 12.6 MB (wq|wk|wv rows)
  u16* wob   = (u16*)ws; ws += (size_t)DD * DD * 2;        //  8.4 MB
  u16* QKVb  = (u16*)ws; ws += (size_t)MM * QSTR * 2;      // 25.2 MB
  u16* Yb    = (u16*)ws;                                   // 16.8 MB

  // 1) fused converts: x, wq, wk, wv, wo in ONE launch
  cvt_all<<<2048, 256, 0, stream>>>(x, wq, wk, wv, wo, xb, wqkvb, wob);

  // 2) fused QKV projection: 256^2 8-phase-style GEMM (192 blocks)
  gemm_qkv<<<dim3(QSTR / 256, MM / 256), 512, 0, stream>>>(xb, wqkvb, QKVb, MM, QSTR, DD);

  // 3) RoPE on K only (Q-rope fused into attention)
  rope_k<<<(MM * NKVH * 64) / 256, 256, 0, stream>>>(QKVb + DD, rope);

  // 4) attention (swapped-QK^T softmax path)
  attn_kernel<<<BB * NH * (TT / QBLK / 2), 512, 0, stream>>>(QKVb, rope, Yb);

  // 5) output projection (fp32 out, m97 structure + T1)
  gemm_bt<false><<<dim3(DD / 128, MM / 128), 256, 0, stream>>>(Yb, wob, out, MM, DD, DD);
}

// Round 10
// 212.297 us; speedup vs baseline: 1.0692x; 1.0254x over previous
//
#include <hip/hip_runtime.h>

// ---------- types & helpers ----------
typedef unsigned short u16;
typedef float   f32x4  __attribute__((ext_vector_type(4)));
typedef short   short8 __attribute__((ext_vector_type(8)));
typedef __bf16  bf16x8 __attribute__((ext_vector_type(8)));
typedef float   float4v __attribute__((ext_vector_type(4)));
typedef unsigned short u16x4 __attribute__((ext_vector_type(4)));

// native HW bf16 convert (RNE) — do not hand-roll (T12/m240)
static __device__ __forceinline__ u16 f2b(float f) {
  return __builtin_bit_cast(u16, (__bf16)f);
}
static __device__ __forceinline__ float b2f(u16 h) {
  union { unsigned u; float f; } v; v.u = ((unsigned)h) << 16;
  return v.f;
}
static __device__ __forceinline__ f32x4 mfma_bf16(short8 a, short8 b, f32x4 c) {
  return __builtin_amdgcn_mfma_f32_16x16x32_bf16(
      __builtin_bit_cast(bf16x8, a), __builtin_bit_cast(bf16x8, b), c, 0, 0, 0);
}
// async global->LDS, 16B per lane; lds ptr must be wave-uniform base (HW adds lane*16)
static __device__ __forceinline__ void gload_lds16(const u16* g, u16* l) {
  __builtin_amdgcn_global_load_lds(
      (const __attribute__((address_space(1))) unsigned int*)g,
      (__attribute__((address_space(3))) unsigned int*)l, 16, 0, 0);
}

// ---------- problem constants ----------
#define BB 2
#define TT 2048
#define DD 2048
#define NH 16
#define NKVH 4
#define HD 128
#define MM (BB * TT)          // 4096 rows
#define QSTR 3072             // fused QKV projection row: [Q(2048) | K(512) | V(512)]
#define QSCALE 0.08838834764831845f

// ---------- fused fp32 -> bf16 convert (all 5 tensors, 1 launch) ----------
#define N4_X   ((MM * DD) / 4)
#define N4_WQ  ((DD * DD) / 4)
#define N4_WKV ((NKVH * HD * DD) / 4)
#define N4_WO  ((DD * DD) / 4)
#define N4_TOT (N4_X + N4_WQ + 2 * N4_WKV + N4_WO)

__global__ __launch_bounds__(256) void cvt_all(const float* __restrict__ x,
                                               const float* __restrict__ wq,
                                               const float* __restrict__ wk,
                                               const float* __restrict__ wv,
                                               const float* __restrict__ wo,
                                               u16* __restrict__ xb,
                                               u16* __restrict__ wqkvb,
                                               u16* __restrict__ wob) {
  int stride = gridDim.x * blockDim.x;
  for (int i = blockIdx.x * blockDim.x + threadIdx.x; i < N4_TOT; i += stride) {
    const float4v* src;
    u16x4* dst;
    int off;
    if (i < N4_X) {
      src = (const float4v*)x; dst = (u16x4*)xb; off = i;
    } else if (i < N4_X + N4_WQ) {
      src = (const float4v*)wq; dst = (u16x4*)wqkvb; off = i - N4_X;
    } else if (i < N4_X + N4_WQ + N4_WKV) {
      src = (const float4v*)wk; dst = (u16x4*)wqkvb + N4_WQ; off = i - (N4_X + N4_WQ);
    } else if (i < N4_X + N4_WQ + 2 * N4_WKV) {
      src = (const float4v*)wv; dst = (u16x4*)wqkvb + N4_WQ + N4_WKV;
      off = i - (N4_X + N4_WQ + N4_WKV);
    } else {
      src = (const float4v*)wo; dst = (u16x4*)wob; off = i - (N4_X + N4_WQ + 2 * N4_WKV);
    }
    float4v v = src[off];
    u16x4 o;
    o[0] = f2b(v[0]); o[1] = f2b(v[1]); o[2] = f2b(v[2]); o[3] = f2b(v[3]);
    dst[off] = o;
  }
}

// ---------- RoPE on K only (Q-rope is fused into the attention prologue) ----------
__global__ __launch_bounds__(256) void rope_k(u16* __restrict__ K,
                                              const float* __restrict__ rope) {
  int idx = blockIdx.x * 256 + threadIdx.x;
  int i  = idx & 63;
  int h  = (idx >> 6) & (NKVH - 1);
  int bt = idx >> 8;
  int t  = bt & (TT - 1);
  size_t base = (size_t)bt * QSTR + h * HD + i;
  float x1 = b2f(K[base]);
  float x2 = b2f(K[base + 64]);
  float c = rope[t * 128 + 2 * i];
  float s = rope[t * 128 + 2 * i + 1];
  K[base]      = f2b(x1 * c - x2 * s);
  K[base + 64] = f2b(x1 * s + x2 * c);
}

// ---------- 8-phase-style 256x256 GEMM (QKV projection) ----------
__global__ __launch_bounds__(512, 2) void gemm_qkv(const u16* __restrict__ A,
                                                   const u16* __restrict__ W,
                                                   u16* __restrict__ C,
                                                   int M, int N, int K) {
  __shared__ __align__(16) u16 As[2][2][128 * 64];  // [buf][half][r*64+swz]
  __shared__ __align__(16) u16 Ws[2][2][128 * 64];

  const int tid = threadIdx.x, lane = tid & 63, wid = tid >> 6;
  const int wm = wid >> 2, wn = wid & 3;
  const int l15 = lane & 15, lh = lane >> 4;

  // T1 bijective XCD swizzle (nwg = 192, %8 == 0)
  const int nwg = gridDim.x * gridDim.y;
  const int lin = blockIdx.y * gridDim.x + blockIdx.x;
  const int swz = (lin & 7) * (nwg >> 3) + (lin >> 3);
  const int brow = (swz / gridDim.x) * 256, bcol = (swz % gridDim.x) * 256;

  const int srp = wid * 8 + (lane >> 3);
  const int gsw = ((lane & 7) ^ (lane >> 3)) << 3;
  const u16* sa[2][2];
  const u16* sw[2][2];
#pragma unroll
  for (int mh = 0; mh < 2; ++mh)
#pragma unroll
    for (int i = 0; i < 2; ++i) {
      sa[mh][i] = A + (size_t)(brow + mh * 128 + i * 64 + srp) * K + gsw;
      sw[mh][i] = W + (size_t)(bcol + mh * 128 + i * 64 + srp) * K + gsw;
    }

  f32x4 acc[8][4];
#pragma unroll
  for (int mi = 0; mi < 8; ++mi)
#pragma unroll
    for (int ni = 0; ni < 4; ++ni) acc[mi][ni] = (f32x4)0.0f;

  const int nk = K >> 6;  // 64-wide K tiles

  auto issue = [&](int t, int p) {
#pragma unroll
    for (int mh = 0; mh < 2; ++mh)
#pragma unroll
      for (int i = 0; i < 2; ++i) {
        gload_lds16(sa[mh][i] + t * 64, &As[p][mh][i * 4096 + wid * 512]);
        gload_lds16(sw[mh][i] + t * 64, &Ws[p][mh][i * 4096 + wid * 512]);
      }
  };

  issue(0, 0);
  for (int t = 0; t < nk; ++t) {
    const int p = t & 1;
    if (t + 1 < nk) {
      issue(t + 1, p ^ 1);  // next tile: 8 loads stay in flight across compute
      asm volatile("s_waitcnt vmcnt(8)" ::: "memory");  // tile t's 8 landed
    } else {
      asm volatile("s_waitcnt vmcnt(0)" ::: "memory");
    }
    __builtin_amdgcn_sched_barrier(0);
    __builtin_amdgcn_s_barrier();   // B1: all waves' tile-t stages visible
    __builtin_amdgcn_sched_barrier(0);

    const u16* Ab = &As[p][wm][0];
    const u16* Wb = &Ws[p][wn >> 1][0];
    const int wrow = (wn & 1) * 64;

    short8 af[4][2], bf[2][2];
    // ---- phase 0: A lo half-frags + B cols 0..31
#pragma unroll
    for (int mi = 0; mi < 4; ++mi)
#pragma unroll
      for (int ks = 0; ks < 2; ++ks) {
        int rh = mi * 16 + l15;
        af[mi][ks] = *(const short8*)&Ab[rh * 64 + (((ks * 4 + lh) ^ (rh & 7)) << 3)];
      }
#pragma unroll
    for (int ni = 0; ni < 2; ++ni)
#pragma unroll
      for (int ks = 0; ks < 2; ++ks) {
        int rh = wrow + ni * 16 + l15;
        bf[ni][ks] = *(const short8*)&Wb[rh * 64 + (((ks * 4 + lh) ^ (rh & 7)) << 3)];
      }
    __builtin_amdgcn_s_setprio(1);
#pragma unroll
    for (int mi = 0; mi < 4; ++mi)
#pragma unroll
      for (int ni = 0; ni < 2; ++ni)
#pragma unroll
        for (int ks = 0; ks < 2; ++ks)
          acc[mi][ni] = mfma_bf16(af[mi][ks], bf[ni][ks], acc[mi][ni]);
    __builtin_amdgcn_s_setprio(0);
    __builtin_amdgcn_s_barrier();
    // ---- phase 1: B cols 32..63 (A kept)
#pragma unroll
    for (int ni = 0; ni < 2; ++ni)
#pragma unroll
      for (int ks = 0; ks < 2; ++ks) {
        int rh = wrow + (2 + ni) * 16 + l15;
        bf[ni][ks] = *(const short8*)&Wb[rh * 64 + (((ks * 4 + lh) ^ (rh & 7)) << 3)];
      }
    __builtin_amdgcn_s_setprio(1);
#pragma unroll
    for (int mi = 0; mi < 4; ++mi)
#pragma unroll
      for (int ni = 0; ni < 2; ++ni)
#pragma unroll
        for (int ks = 0; ks < 2; ++ks)
          acc[mi][2 + ni] = mfma_bf16(af[mi][ks], bf[ni][ks], acc[mi][2 + ni]);
    __builtin_amdgcn_s_setprio(0);
    __builtin_amdgcn_s_barrier();
    // ---- phase 2: A hi half-frags (B cols 32..63 kept)
#pragma unroll
    for (int mi = 0; mi < 4; ++mi)
#pragma unroll
      for (int ks = 0; ks < 2; ++ks) {
        int rh = (4 + mi) * 16 + l15;
        af[mi][ks] = *(const short8*)&Ab[rh * 64 + (((ks * 4 + lh) ^ (rh & 7)) << 3)];
      }
    __builtin_amdgcn_s_setprio(1);
#pragma unroll
    for (int mi = 0; mi < 4; ++mi)
#pragma unroll
      for (int ni = 0; ni < 2; ++ni)
#pragma unroll
        for (int ks = 0; ks < 2; ++ks)
          acc[4 + mi][2 + ni] = mfma_bf16(af[mi][ks], bf[ni][ks], acc[4 + mi][2 + ni]);
    __builtin_amdgcn_s_setprio(0);
    __builtin_amdgcn_s_barrier();
    // ---- phase 3: B cols 0..31 again (A hi kept)
#pragma unroll
    for (int ni = 0; ni < 2; ++ni)
#pragma unroll
      for (int ks = 0; ks < 2; ++ks) {
        int rh = wrow + ni * 16 + l15;
        bf[ni][ks] = *(const short8*)&Wb[rh * 64 + (((ks * 4 + lh) ^ (rh & 7)) << 3)];
      }
    __builtin_amdgcn_s_setprio(1);
#pragma unroll
    for (int mi = 0; mi < 4; ++mi)
#pragma unroll
      for (int ni = 0; ni < 2; ++ni)
#pragma unroll
        for (int ks = 0; ks < 2; ++ks)
          acc[4 + mi][ni] = mfma_bf16(af[mi][ks], bf[ni][ks], acc[4 + mi][ni]);
    __builtin_amdgcn_s_setprio(0);

    // B2: all reads of buf[p] complete before next iter's issue overwrites it
    asm volatile("s_waitcnt lgkmcnt(0)" ::: "memory");
    __builtin_amdgcn_sched_barrier(0);
    __builtin_amdgcn_s_barrier();
    __builtin_amdgcn_sched_barrier(0);
  }

  // ---- epilogue
#pragma unroll
  for (int mi = 0; mi < 8; ++mi)
#pragma unroll
    for (int ni = 0; ni < 4; ++ni)
#pragma unroll
      for (int j = 0; j < 4; ++j) {
        int row = brow + wm * 128 + mi * 16 + lh * 4 + j;
        int col = bcol + wn * 64 + ni * 16 + l15;
        C[(size_t)row * N + col] = f2b(acc[mi][ni][j]);
      }
}

// ---------- 256x128 counted-vmcnt GEMM (WO projection, fp32 out) ----------
// Same schedule family as gemm_qkv, sized so the grid fills all 256 CUs:
// BM=256, BN=128 -> (2048/128)x(4096/256) = 256 blocks, 1/CU. BK=64,
// 8 waves (wm in {0,1} over A-halves, wn in 0..3 over 32-col strips),
// per-wave 128x32, acc 8x2. 6 gload_lds/tile -> vmcnt(6). LDS 96KB.
__global__ __launch_bounds__(512, 2) void gemm_wo(const u16* __restrict__ A,
                                                  const u16* __restrict__ W,
                                                  float* __restrict__ C,
                                                  int M, int N, int K) {
  __shared__ __align__(16) u16 As[2][2][128 * 64];  // [buf][half][r*64+swz] 64KB
  __shared__ __align__(16) u16 Ws[2][128 * 64];     // [buf][r*64+swz]       32KB

  const int tid = threadIdx.x, lane = tid & 63, wid = tid >> 6;
  const int wm = wid >> 2, wn = wid & 3;
  const int l15 = lane & 15, lh = lane >> 4;

  // T1 bijective XCD swizzle (nwg = 256, %8 == 0)
  const int nwg = gridDim.x * gridDim.y;
  const int lin = blockIdx.y * gridDim.x + blockIdx.x;
  const int swz = (lin & 7) * (nwg >> 3) + (lin >> 3);
  const int brow = (swz / gridDim.x) * 256, bcol = (swz % gridDim.x) * 128;

  const int srp = wid * 8 + (lane >> 3);
  const int gsw = ((lane & 7) ^ (lane >> 3)) << 3;
  const u16* sa[2][2];
  const u16* sw2[2];
#pragma unroll
  for (int mh = 0; mh < 2; ++mh)
#pragma unroll
    for (int i = 0; i < 2; ++i)
      sa[mh][i] = A + (size_t)(brow + mh * 128 + i * 64 + srp) * K + gsw;
#pragma unroll
  for (int i = 0; i < 2; ++i)
    sw2[i] = W + (size_t)(bcol + i * 64 + srp) * K + gsw;

  f32x4 acc[8][2];
#pragma unroll
  for (int mi = 0; mi < 8; ++mi)
#pragma unroll
    for (int ni = 0; ni < 2; ++ni) acc[mi][ni] = (f32x4)0.0f;

  const int nk = K >> 6;

  auto issue = [&](int t, int p) {
#pragma unroll
    for (int mh = 0; mh < 2; ++mh)
#pragma unroll
      for (int i = 0; i < 2; ++i)
        gload_lds16(sa[mh][i] + t * 64, &As[p][mh][i * 4096 + wid * 512]);
#pragma unroll
    for (int i = 0; i < 2; ++i)
      gload_lds16(sw2[i] + t * 64, &Ws[p][i * 4096 + wid * 512]);
  };

  issue(0, 0);
  for (int t = 0; t < nk; ++t) {
    const int p = t & 1;
    if (t + 1 < nk) {
      issue(t + 1, p ^ 1);  // 6 loads for tile t+1 stay in flight
      asm volatile("s_waitcnt vmcnt(6)" ::: "memory");  // tile t's 6 landed
    } else {
      asm volatile("s_waitcnt vmcnt(0)" ::: "memory");
    }
    __builtin_amdgcn_sched_barrier(0);
    __builtin_amdgcn_s_barrier();   // B1: tile-t stages visible
    __builtin_amdgcn_sched_barrier(0);

    const u16* Ab = &As[p][wm][0];
    const u16* Wb = &Ws[p][0];

    short8 af[4][2], bf[2][2];
    // B frags (cols wn*32 + {0,16}), reused across both phases
#pragma unroll
    for (int ni = 0; ni < 2; ++ni)
#pragma unroll
      for (int ks = 0; ks < 2; ++ks) {
        int rh = wn * 32 + ni * 16 + l15;
        bf[ni][ks] = *(const short8*)&Wb[rh * 64 + (((ks * 4 + lh) ^ (rh & 7)) << 3)];
      }
    // ---- phase 0: A lo half
#pragma unroll
    for (int mi = 0; mi < 4; ++mi)
#pragma unroll
      for (int ks = 0; ks < 2; ++ks) {
        int rh = mi * 16 + l15;
        af[mi][ks] = *(const short8*)&Ab[rh * 64 + (((ks * 4 + lh) ^ (rh & 7)) << 3)];
      }
    __builtin_amdgcn_s_setprio(1);
#pragma unroll
    for (int mi = 0; mi < 4; ++mi)
#pragma unroll
      for (int ni = 0; ni < 2; ++ni)
#pragma unroll
        for (int ks = 0; ks < 2; ++ks)
          acc[mi][ni] = mfma_bf16(af[mi][ks], bf[ni][ks], acc[mi][ni]);
    __builtin_amdgcn_s_setprio(0);
    __builtin_amdgcn_s_barrier();
    // ---- phase 1: A hi half
#pragma unroll
    for (int mi = 0; mi < 4; ++mi)
#pragma unroll
      for (int ks = 0; ks < 2; ++ks) {
        int rh = (4 + mi) * 16 + l15;
        af[mi][ks] = *(const short8*)&Ab[rh * 64 + (((ks * 4 + lh) ^ (rh & 7)) << 3)];
      }
    __builtin_amdgcn_s_setprio(1);
#pragma unroll
    for (int mi = 0; mi < 4; ++mi)
#pragma unroll
      for (int ni = 0; ni < 2; ++ni)
#pragma unroll
        for (int ks = 0; ks < 2; ++ks)
          acc[4 + mi][ni] = mfma_bf16(af[mi][ks], bf[ni][ks], acc[4 + mi][ni]);
    __builtin_amdgcn_s_setprio(0);

    // B2: all reads of buf[p] complete before next iter's issue overwrites it
    asm volatile("s_waitcnt lgkmcnt(0)" ::: "memory");
    __builtin_amdgcn_sched_barrier(0);
    __builtin_amdgcn_s_barrier();
    __builtin_amdgcn_sched_barrier(0);
  }

  // ---- epilogue (fp32)
#pragma unroll
  for (int mi = 0; mi < 8; ++mi)
#pragma unroll
    for (int ni = 0; ni < 2; ++ni)
#pragma unroll
      for (int j = 0; j < 4; ++j) {
        int row = brow + wm * 128 + mi * 16 + lh * 4 + j;
        int col = bcol + wn * 32 + ni * 16 + l15;
        C[(size_t)row * N + col] = acc[mi][ni][j];
      }
}

// ---------- fused causal GQA flash attention (R9, unchanged) ----------
#define QBLK 128
#define KVBLK 128

static __device__ __forceinline__ void attn_tile(
    const short8* qa, f32x4* o, float& l, float& m,
    int qrow0, int kv0,
    const u16* Ks, const unsigned* Vt32, u16* myP,
    int l15, int lh) {
  if (kv0 > qrow0 + 15) return;   // fully masked for this wave

  // ---- swapped QK^T: st[nt][j] = S[kv = kv0+nt*16+lh*4+j][q = qrow0+l15]
  f32x4 st[4];
#pragma unroll
  for (int nt = 0; nt < 4; ++nt) st[nt] = (f32x4)0.0f;
  __builtin_amdgcn_s_setprio(1);
#pragma unroll
  for (int nt = 0; nt < 4; ++nt) {
    const u16* krow = &Ks[(nt * 16 + l15) * 136 + (lh << 3)];
#pragma unroll
    for (int kk = 0; kk < 4; ++kk) {
      short8 kb = *(const short8*)(krow + kk * 32);
      st[nt] = mfma_bf16(kb, qa[kk], st[nt]);
    }
  }
  __builtin_amdgcn_s_setprio(0);

  // ---- causal mask: kv > q  <=>  (kv0 + lh*4 - qrow0 - l15) + nt*16 + j > 0
  const int kvq = kv0 + lh * 4 - qrow0 - l15;
#pragma unroll
  for (int nt = 0; nt < 4; ++nt)
#pragma unroll
    for (int j = 0; j < 4; ++j)
      if (kvq + nt * 16 + j > 0) st[nt][j] = -1e30f;

  // ---- in-lane row max (q = l15), then reduce across the 4 lh groups
  float mt = st[0][0];
#pragma unroll
  for (int nt = 0; nt < 4; ++nt)
#pragma unroll
    for (int j = 0; j < 4; ++j) mt = fmaxf(mt, st[nt][j]);
  mt = fmaxf(mt, __shfl_xor(mt, 16));
  mt = fmaxf(mt, __shfl_xor(mt, 32));

  // ---- defer-max (T13): rescale only when max grew by > 8
  if (!__all(mt - m <= 8.0f)) {
    float mn = fmaxf(m, mt);
    float a = __expf(m - mn);
    m = mn;
    l *= a;
    float aj[4];
#pragma unroll
    for (int j = 0; j < 4; ++j) aj[j] = __shfl(a, lh * 4 + j);
#pragma unroll
    for (int n = 0; n < 8; ++n)
#pragma unroll
      for (int j = 0; j < 4; ++j) o[n][j] *= aj[j];
  }

  // ---- P = exp(S - m); row-sum accumulated in-lane (partial over this lh)
  f32x4 p[4];
  float ps = 0.0f;
#pragma unroll
  for (int nt = 0; nt < 4; ++nt) {
#pragma unroll
    for (int j = 0; j < 4; ++j) p[nt][j] = __expf(st[nt][j] - m);
    ps += (p[nt][0] + p[nt][1]) + (p[nt][2] + p[nt][3]);
  }
  l += ps;

  // ---- P -> per-wave LDS, pair-packed b32 at elem l15*72 + kv
  unsigned* P32 = (unsigned*)myP;
  const int pb = l15 * 36 + lh * 2;
#pragma unroll
  for (int nt = 0; nt < 4; ++nt)
#pragma unroll
    for (int jj = 0; jj < 2; ++jj)
      P32[pb + nt * 8 + jj] =
          (unsigned)f2b(p[nt][2 * jj]) | ((unsigned)f2b(p[nt][2 * jj + 1]) << 16);

  // ---- PV (read pattern unchanged from verified kernel)
  __builtin_amdgcn_s_setprio(1);
#pragma unroll
  for (int c = 0; c < 2; ++c) {
    short8 pa = *(const short8*)&myP[l15 * 72 + c * 32 + (lh << 3)];
#pragma unroll
    for (int nt2 = 0; nt2 < 8; ++nt2) {
      int d = nt2 * 16 + l15;
      int byteoff = (d * 144 + (c * 32 + lh * 8) * 2) ^ (((d >> 3) & 7) << 4);
      short8 vb = *(const short8*)((const char*)Vt32 + byteoff);
      o[nt2] = mfma_bf16(pa, vb, o[nt2]);
    }
  }
  __builtin_amdgcn_s_setprio(0);
}

__global__ __launch_bounds__(512) void attn_kernel(const u16* __restrict__ QKV,
                                                   const float* __restrict__ rope,
                                                   u16* __restrict__ Y) {
  __shared__ __align__(16) u16 Ks[2][64 * 136];        // 2 x 17408 B
  __shared__ __align__(16) unsigned Vt32[2][128 * 36]; // 2 x 18432 B
  __shared__ __align__(16) u16 Ps[8][16 * 72];         // 18432 B

  const int tid = threadIdx.x, lane = tid & 63, wid = tid >> 6;
  const int l15 = lane & 15, lh = lane >> 4;
  const int bid = blockIdx.x;
  const int qpair = bid & 7;
  const int h = (bid >> 3) & 15;
  const int b = bid >> 7;
  const int kvh = h >> 2;
  const int qtA = qpair, qtB = 15 - qpair;
  const int rowA = qtA * QBLK + wid * 16;
  const int rowB = qtB * QBLK + wid * 16;

  const u16* Kb_ = QKV + (size_t)b * TT * QSTR + DD + kvh * HD;  // K cols
  const u16* Vb_ = Kb_ + NKVH * HD;                              // V cols

  short8 qaA[4], qaB[4];
  {
    const u16* qA = QKV + (size_t)(b * TT + rowA + l15) * QSTR + h * HD + (lh << 3);
    const u16* qB = QKV + (size_t)(b * TT + rowB + l15) * QSTR + h * HD + (lh << 3);
#pragma unroll
    for (int kk = 0; kk < 4; ++kk) {
      qaA[kk] = *(const short8*)(qA + kk * 32);
      qaB[kk] = *(const short8*)(qB + kk * 32);
    }
  }
  // ---- fused Q-RoPE + softmax scale (pair (i, i+64) = qa[kk] / qa[kk+2])
  {
    const float* rpA = rope + (size_t)(rowA + l15) * 128;
    const float* rpB = rope + (size_t)(rowB + l15) * 128;
#pragma unroll
    for (int kk = 0; kk < 2; ++kk)
#pragma unroll
      for (int e = 0; e < 8; ++e) {
        const int i2 = 2 * (kk * 32 + (lh << 3) + e);
        float c = rpA[i2], s = rpA[i2 + 1];
        float x1 = b2f((u16)qaA[kk][e]), x2 = b2f((u16)qaA[kk + 2][e]);
        qaA[kk][e]     = (short)f2b(QSCALE * (x1 * c - x2 * s));
        qaA[kk + 2][e] = (short)f2b(QSCALE * (x1 * s + x2 * c));
        float cb = rpB[i2], sb = rpB[i2 + 1];
        float y1 = b2f((u16)qaB[kk][e]), y2 = b2f((u16)qaB[kk + 2][e]);
        qaB[kk][e]     = (short)f2b(QSCALE * (y1 * cb - y2 * sb));
        qaB[kk + 2][e] = (short)f2b(QSCALE * (y1 * sb + y2 * cb));
      }
  }

  f32x4 oA[8], oB[8];
  float lA = 0.0f, lB = 0.0f;
  float mA = -1e30f, mB = -1e30f;
#pragma unroll
  for (int n = 0; n < 8; ++n) { oA[n] = (f32x4)0.0f; oB[n] = (f32x4)0.0f; }

  const int kvend = (qtB + 1) * QBLK;   // multiple of 128

  // staging registers (T14: issue early, write late); 128 KV rows per pass
  short8 kreg[4], vreg[4];
  const int srow = tid >> 4;           // 0..31
  const int sc8 = (tid & 15) << 3;

  auto issue = [&](int kv0) {
    kreg[0] = *(const short8*)&Kb_[(size_t)(kv0 + srow) * QSTR + sc8];
    kreg[1] = *(const short8*)&Kb_[(size_t)(kv0 + 32 + srow) * QSTR + sc8];
    kreg[2] = *(const short8*)&Kb_[(size_t)(kv0 + 64 + srow) * QSTR + sc8];
    kreg[3] = *(const short8*)&Kb_[(size_t)(kv0 + 96 + srow) * QSTR + sc8];
    vreg[0] = *(const short8*)&Vb_[(size_t)(kv0 + 2 * srow) * QSTR + sc8];
    vreg[1] = *(const short8*)&Vb_[(size_t)(kv0 + 2 * srow + 1) * QSTR + sc8];
    vreg[2] = *(const short8*)&Vb_[(size_t)(kv0 + 64 + 2 * srow) * QSTR + sc8];
    vreg[3] = *(const short8*)&Vb_[(size_t)(kv0 + 64 + 2 * srow + 1) * QSTR + sc8];
  };

  issue(0);
  for (int kv0 = 0; kv0 < kvend; kv0 += KVBLK) {
    __syncthreads();   // previous tile's LDS reads done
    *(short8*)&Ks[0][srow * 136 + sc8] = kreg[0];
    *(short8*)&Ks[0][(srow + 32) * 136 + sc8] = kreg[1];
    *(short8*)&Ks[1][srow * 136 + sc8] = kreg[2];
    *(short8*)&Ks[1][(srow + 32) * 136 + sc8] = kreg[3];
#pragma unroll
    for (int e = 0; e < 8; ++e) {
      int d = sc8 + e;
      unsigned pk0 = (unsigned)(u16)vreg[0][e] | ((unsigned)(u16)vreg[1][e] << 16);
      unsigned pk1 = (unsigned)(u16)vreg[2][e] | ((unsigned)(u16)vreg[3][e] << 16);
      int byteoff = (d * 144 + 4 * srow) ^ (((d >> 3) & 7) << 4);
      *(unsigned*)((char*)&Vt32[0][0] + byteoff) = pk0;
      *(unsigned*)((char*)&Vt32[1][0] + byteoff) = pk1;
    }
    __syncthreads();   // staged tile visible
    if (kv0 + KVBLK < kvend) issue(kv0 + KVBLK);  // overlap next loads with compute

    attn_tile(qaA, oA, lA, mA, rowA, kv0,      &Ks[0][0], &Vt32[0][0], &Ps[wid][0], l15, lh);
    attn_tile(qaA, oA, lA, mA, rowA, kv0 + 64, &Ks[1][0], &Vt32[1][0], &Ps[wid][0], l15, lh);
    attn_tile(qaB, oB, lB, mB, rowB, kv0,      &Ks[0][0], &Vt32[0][0], &Ps[wid][0], l15, lh);
    attn_tile(qaB, oB, lB, mB, rowB, kv0 + 64, &Ks[1][0], &Vt32[1][0], &Ps[wid][0], l15, lh);
  }

  // ---- epilogue: total row-sums (reduce over lh), redistribute to q=lh*4+j
  lA += __shfl_xor(lA, 16); lA += __shfl_xor(lA, 32);
  lB += __shfl_xor(lB, 16); lB += __shfl_xor(lB, 32);
  f32x4 invA, invB;
#pragma unroll
  for (int j = 0; j < 4; ++j) {
    invA[j] = __builtin_amdgcn_rcpf(__shfl(lA, lh * 4 + j));
    invB[j] = __builtin_amdgcn_rcpf(__shfl(lB, lh * 4 + j));
  }
#pragma unroll
  for (int nt = 0; nt < 8; ++nt)
#pragma unroll
    for (int j = 0; j < 4; ++j) {
      Y[(size_t)(b * TT + rowA + lh * 4 + j) * DD + h * HD + nt * 16 + l15] =
          f2b(oA[nt][j] * invA[j]);
      Y[(size_t)(b * TT + rowB + lh * 4 + j) * DD + h * HD + nt * 16 + l15] =
          f2b(oB[nt][j] * invB[j]);
    }
}

// ---------- launcher ----------
extern "C" void kernel_launch(void* const* d_in, const int* in_sizes, int n_in,
                              void* d_out, int out_size, void* d_ws, size_t ws_size,
                              hipStream_t stream) {
  const float* x    = (const float*)d_in[0];
  const float* rope = (const float*)d_in[1];
  const float* wq   = (const float*)d_in[2];
  const float* wk   = (const float*)d_in[3];
  const float* wv   = (const float*)d_in[4];
  const float* wo   = (const float*)d_in[5];
  float* out = (float*)d_out;

  char* ws = (char*)d_ws;
  u16* xb    = (u16*)ws; ws += (size_t)MM * DD * 2;        // 16.8 MB
  u16* wqkvb = (u16*)ws; ws += (size_t)QSTR * DD * 2;      // 12.6 MB (wq|wk|wv rows)
  u16* wob   = (u16*)ws; ws += (size_t)DD * DD * 2;        //  8.4 MB
  u16* QKVb  = (u16*)ws; ws += (size_t)MM * QSTR * 2;      // 25.2 MB
  u16* Yb    = (u16*)ws;                                   // 16.8 MB

  // 1) fused converts: x, wq, wk, wv, wo in ONE launch
  cvt_all<<<2048, 256, 0, stream>>>(x, wq, wk, wv, wo, xb, wqkvb, wob);

  // 2) fused QKV projection: 256^2 counted-vmcnt GEMM (192 blocks)
  gemm_qkv<<<dim3(QSTR / 256, MM / 256), 512, 0, stream>>>(xb, wqkvb, QKVb, MM, QSTR, DD);

  // 3) RoPE on K only (Q-rope fused into attention)
  rope_k<<<(MM * NKVH * 64) / 256, 256, 0, stream>>>(QKVb + DD, rope);

  // 4) attention (swapped-QK^T softmax path)
  attn_kernel<<<BB * NH * (TT / QBLK / 2), 512, 0, stream>>>(QKVb, rope, Yb);

  // 5) output projection: 256x128 counted-vmcnt GEMM (256 blocks, 1/CU)
  gemm_wo<<<dim3(DD / 128, MM / 256), 512, 0, stream>>>(Yb, wob, out, MM, DD, DD);
}

// Round 11
// 200.052 us; speedup vs baseline: 1.1346x; 1.0612x over previous
//
#include <hip/hip_runtime.h>

// ---------- types & helpers ----------
typedef unsigned short u16;
typedef float   f32x4  __attribute__((ext_vector_type(4)));
typedef short   short8 __attribute__((ext_vector_type(8)));
typedef __bf16  bf16x8 __attribute__((ext_vector_type(8)));
typedef float   float4v __attribute__((ext_vector_type(4)));
typedef unsigned short u16x4 __attribute__((ext_vector_type(4)));

// native HW bf16 convert (RNE) — do not hand-roll (T12/m240)
static __device__ __forceinline__ u16 f2b(float f) {
  return __builtin_bit_cast(u16, (__bf16)f);
}
static __device__ __forceinline__ float b2f(u16 h) {
  union { unsigned u; float f; } v; v.u = ((unsigned)h) << 16;
  return v.f;
}
static __device__ __forceinline__ f32x4 mfma_bf16(short8 a, short8 b, f32x4 c) {
  return __builtin_amdgcn_mfma_f32_16x16x32_bf16(
      __builtin_bit_cast(bf16x8, a), __builtin_bit_cast(bf16x8, b), c, 0, 0, 0);
}
// async global->LDS, 16B per lane; lds ptr must be wave-uniform base (HW adds lane*16)
static __device__ __forceinline__ void gload_lds16(const u16* g, u16* l) {
  __builtin_amdgcn_global_load_lds(
      (const __attribute__((address_space(1))) unsigned int*)g,
      (__attribute__((address_space(3))) unsigned int*)l, 16, 0, 0);
}

// ---------- problem constants ----------
#define BB 2
#define TT 2048
#define DD 2048
#define NH 16
#define NKVH 4
#define HD 128
#define MM (BB * TT)          // 4096 rows
#define QSTR 3072             // fused QKV projection row: [Q(2048) | K(512) | V(512)]
#define QSCALE 0.08838834764831845f

// ---------- fused fp32 -> bf16 convert (all 5 tensors, 1 launch) ----------
#define N4_X   ((MM * DD) / 4)
#define N4_WQ  ((DD * DD) / 4)
#define N4_WKV ((NKVH * HD * DD) / 4)
#define N4_WO  ((DD * DD) / 4)
#define N4_TOT (N4_X + N4_WQ + 2 * N4_WKV + N4_WO)

__global__ __launch_bounds__(256) void cvt_all(const float* __restrict__ x,
                                               const float* __restrict__ wq,
                                               const float* __restrict__ wk,
                                               const float* __restrict__ wv,
                                               const float* __restrict__ wo,
                                               u16* __restrict__ xb,
                                               u16* __restrict__ wqkvb,
                                               u16* __restrict__ wob) {
  int stride = gridDim.x * blockDim.x;
  for (int i = blockIdx.x * blockDim.x + threadIdx.x; i < N4_TOT; i += stride) {
    const float4v* src;
    u16x4* dst;
    int off;
    if (i < N4_X) {
      src = (const float4v*)x; dst = (u16x4*)xb; off = i;
    } else if (i < N4_X + N4_WQ) {
      src = (const float4v*)wq; dst = (u16x4*)wqkvb; off = i - N4_X;
    } else if (i < N4_X + N4_WQ + N4_WKV) {
      src = (const float4v*)wk; dst = (u16x4*)wqkvb + N4_WQ; off = i - (N4_X + N4_WQ);
    } else if (i < N4_X + N4_WQ + 2 * N4_WKV) {
      src = (const float4v*)wv; dst = (u16x4*)wqkvb + N4_WQ + N4_WKV;
      off = i - (N4_X + N4_WQ + N4_WKV);
    } else {
      src = (const float4v*)wo; dst = (u16x4*)wob; off = i - (N4_X + N4_WQ + 2 * N4_WKV);
    }
    float4v v = src[off];
    u16x4 o;
    o[0] = f2b(v[0]); o[1] = f2b(v[1]); o[2] = f2b(v[2]); o[3] = f2b(v[3]);
    dst[off] = o;
  }
}

// ---------- RoPE on K only (Q-rope is fused into the attention prologue) ----------
__global__ __launch_bounds__(256) void rope_k(u16* __restrict__ K,
                                              const float* __restrict__ rope) {
  int idx = blockIdx.x * 256 + threadIdx.x;
  int i  = idx & 63;
  int h  = (idx >> 6) & (NKVH - 1);
  int bt = idx >> 8;
  int t  = bt & (TT - 1);
  size_t base = (size_t)bt * QSTR + h * HD + i;
  float x1 = b2f(K[base]);
  float x2 = b2f(K[base + 64]);
  float c = rope[t * 128 + 2 * i];
  float s = rope[t * 128 + 2 * i + 1];
  K[base]      = f2b(x1 * c - x2 * s);
  K[base + 64] = f2b(x1 * s + x2 * c);
}

// ---------- 256x192 counted-vmcnt GEMM (QKV projection, bf16 out) ----------
// Grid fill fix: (3072/192)x(4096/256) = 256 blocks = exactly 1/CU (the 256^2
// version had only 192 blocks = 75% CU util). Same verified schedule family:
// BK=64, 8 waves (wm in {0,1} A-halves, wn in 0..3 over 48-col strips),
// per-wave 128x48, acc 8x3. 7 gload_lds/tile -> vmcnt(7). LDS 112KB dbuf.
// Pre-swizzled SOURCE + XOR on READ (rule #21): chunk c at row r holds
// global col-group c ^ (r&7); read group g at chunk g ^ (r&7).
__global__ __launch_bounds__(512) void gemm_qkv(const u16* __restrict__ A,
                                                const u16* __restrict__ W,
                                                u16* __restrict__ C,
                                                int M, int N, int K) {
  __shared__ __align__(16) u16 As[2][2][128 * 64];  // [buf][half][r*64+swz] 64KB
  __shared__ __align__(16) u16 Ws[2][192 * 64];     // [buf][r*64+swz]       48KB

  const int tid = threadIdx.x, lane = tid & 63, wid = tid >> 6;
  const int wm = wid >> 2, wn = wid & 3;
  const int l15 = lane & 15, lh = lane >> 4;

  // T1 bijective XCD swizzle (nwg = 256, %8 == 0)
  const int nwg = gridDim.x * gridDim.y;
  const int lin = blockIdx.y * gridDim.x + blockIdx.x;
  const int swz = (lin & 7) * (nwg >> 3) + (lin >> 3);
  const int brow = (swz / gridDim.x) * 256, bcol = (swz % gridDim.x) * 192;

  const int srp = wid * 8 + (lane >> 3);
  const int gsw = ((lane & 7) ^ (lane >> 3)) << 3;
  const u16* sa[2][2];
  const u16* sw3[3];
#pragma unroll
  for (int mh = 0; mh < 2; ++mh)
#pragma unroll
    for (int i = 0; i < 2; ++i)
      sa[mh][i] = A + (size_t)(brow + mh * 128 + i * 64 + srp) * K + gsw;
#pragma unroll
  for (int i = 0; i < 3; ++i)
    sw3[i] = W + (size_t)(bcol + i * 64 + srp) * K + gsw;

  f32x4 acc[8][3];
#pragma unroll
  for (int mi = 0; mi < 8; ++mi)
#pragma unroll
    for (int ni = 0; ni < 3; ++ni) acc[mi][ni] = (f32x4)0.0f;

  const int nk = K >> 6;  // 64-wide K tiles

  auto issue = [&](int t, int p) {
#pragma unroll
    for (int mh = 0; mh < 2; ++mh)
#pragma unroll
      for (int i = 0; i < 2; ++i)
        gload_lds16(sa[mh][i] + t * 64, &As[p][mh][i * 4096 + wid * 512]);
#pragma unroll
    for (int i = 0; i < 3; ++i)
      gload_lds16(sw3[i] + t * 64, &Ws[p][i * 4096 + wid * 512]);
  };

  issue(0, 0);
  for (int t = 0; t < nk; ++t) {
    const int p = t & 1;
    if (t + 1 < nk) {
      issue(t + 1, p ^ 1);  // next tile: 7 loads stay in flight across compute
      asm volatile("s_waitcnt vmcnt(7)" ::: "memory");  // tile t's 7 landed
    } else {
      asm volatile("s_waitcnt vmcnt(0)" ::: "memory");
    }
    __builtin_amdgcn_sched_barrier(0);
    __builtin_amdgcn_s_barrier();   // B1: all waves' tile-t stages visible
    __builtin_amdgcn_sched_barrier(0);

    const u16* Ab = &As[p][wm][0];
    const u16* Wb = &Ws[p][0];

    short8 af[4][2], bf[3][2];
    // B frags (cols wn*48 + {0,16,32}), reused across both phases
#pragma unroll
    for (int ni = 0; ni < 3; ++ni)
#pragma unroll
      for (int ks = 0; ks < 2; ++ks) {
        int rh = wn * 48 + ni * 16 + l15;
        bf[ni][ks] = *(const short8*)&Wb[rh * 64 + (((ks * 4 + lh) ^ (rh & 7)) << 3)];
      }
    // ---- phase 0: A lo half
#pragma unroll
    for (int mi = 0; mi < 4; ++mi)
#pragma unroll
      for (int ks = 0; ks < 2; ++ks) {
        int rh = mi * 16 + l15;
        af[mi][ks] = *(const short8*)&Ab[rh * 64 + (((ks * 4 + lh) ^ (rh & 7)) << 3)];
      }
    __builtin_amdgcn_s_setprio(1);
#pragma unroll
    for (int mi = 0; mi < 4; ++mi)
#pragma unroll
      for (int ni = 0; ni < 3; ++ni)
#pragma unroll
        for (int ks = 0; ks < 2; ++ks)
          acc[mi][ni] = mfma_bf16(af[mi][ks], bf[ni][ks], acc[mi][ni]);
    __builtin_amdgcn_s_setprio(0);
    __builtin_amdgcn_s_barrier();
    // ---- phase 1: A hi half
#pragma unroll
    for (int mi = 0; mi < 4; ++mi)
#pragma unroll
      for (int ks = 0; ks < 2; ++ks) {
        int rh = (4 + mi) * 16 + l15;
        af[mi][ks] = *(const short8*)&Ab[rh * 64 + (((ks * 4 + lh) ^ (rh & 7)) << 3)];
      }
    __builtin_amdgcn_s_setprio(1);
#pragma unroll
    for (int mi = 0; mi < 4; ++mi)
#pragma unroll
      for (int ni = 0; ni < 3; ++ni)
#pragma unroll
        for (int ks = 0; ks < 2; ++ks)
          acc[4 + mi][ni] = mfma_bf16(af[mi][ks], bf[ni][ks], acc[4 + mi][ni]);
    __builtin_amdgcn_s_setprio(0);

    // B2: all reads of buf[p] complete before next iter's issue overwrites it
    asm volatile("s_waitcnt lgkmcnt(0)" ::: "memory");
    __builtin_amdgcn_sched_barrier(0);
    __builtin_amdgcn_s_barrier();
    __builtin_amdgcn_sched_barrier(0);
  }

  // ---- epilogue (bf16)
#pragma unroll
  for (int mi = 0; mi < 8; ++mi)
#pragma unroll
    for (int ni = 0; ni < 3; ++ni)
#pragma unroll
      for (int j = 0; j < 4; ++j) {
        int row = brow + wm * 128 + mi * 16 + lh * 4 + j;
        int col = bcol + wn * 48 + ni * 16 + l15;
        C[(size_t)row * N + col] = f2b(acc[mi][ni][j]);
      }
}

// ---------- 256x128 counted-vmcnt GEMM (WO projection, fp32 out) ----------
// BM=256, BN=128 -> 256 blocks, 1/CU. BK=64, 8 waves, per-wave 128x32,
// acc 8x2. 6 gload_lds/tile -> vmcnt(6). LDS 96KB.
__global__ __launch_bounds__(512, 2) void gemm_wo(const u16* __restrict__ A,
                                                  const u16* __restrict__ W,
                                                  float* __restrict__ C,
                                                  int M, int N, int K) {
  __shared__ __align__(16) u16 As[2][2][128 * 64];  // [buf][half][r*64+swz] 64KB
  __shared__ __align__(16) u16 Ws[2][128 * 64];     // [buf][r*64+swz]       32KB

  const int tid = threadIdx.x, lane = tid & 63, wid = tid >> 6;
  const int wm = wid >> 2, wn = wid & 3;
  const int l15 = lane & 15, lh = lane >> 4;

  // T1 bijective XCD swizzle (nwg = 256, %8 == 0)
  const int nwg = gridDim.x * gridDim.y;
  const int lin = blockIdx.y * gridDim.x + blockIdx.x;
  const int swz = (lin & 7) * (nwg >> 3) + (lin >> 3);
  const int brow = (swz / gridDim.x) * 256, bcol = (swz % gridDim.x) * 128;

  const int srp = wid * 8 + (lane >> 3);
  const int gsw = ((lane & 7) ^ (lane >> 3)) << 3;
  const u16* sa[2][2];
  const u16* sw2[2];
#pragma unroll
  for (int mh = 0; mh < 2; ++mh)
#pragma unroll
    for (int i = 0; i < 2; ++i)
      sa[mh][i] = A + (size_t)(brow + mh * 128 + i * 64 + srp) * K + gsw;
#pragma unroll
  for (int i = 0; i < 2; ++i)
    sw2[i] = W + (size_t)(bcol + i * 64 + srp) * K + gsw;

  f32x4 acc[8][2];
#pragma unroll
  for (int mi = 0; mi < 8; ++mi)
#pragma unroll
    for (int ni = 0; ni < 2; ++ni) acc[mi][ni] = (f32x4)0.0f;

  const int nk = K >> 6;

  auto issue = [&](int t, int p) {
#pragma unroll
    for (int mh = 0; mh < 2; ++mh)
#pragma unroll
      for (int i = 0; i < 2; ++i)
        gload_lds16(sa[mh][i] + t * 64, &As[p][mh][i * 4096 + wid * 512]);
#pragma unroll
    for (int i = 0; i < 2; ++i)
      gload_lds16(sw2[i] + t * 64, &Ws[p][i * 4096 + wid * 512]);
  };

  issue(0, 0);
  for (int t = 0; t < nk; ++t) {
    const int p = t & 1;
    if (t + 1 < nk) {
      issue(t + 1, p ^ 1);  // 6 loads for tile t+1 stay in flight
      asm volatile("s_waitcnt vmcnt(6)" ::: "memory");  // tile t's 6 landed
    } else {
      asm volatile("s_waitcnt vmcnt(0)" ::: "memory");
    }
    __builtin_amdgcn_sched_barrier(0);
    __builtin_amdgcn_s_barrier();   // B1: tile-t stages visible
    __builtin_amdgcn_sched_barrier(0);

    const u16* Ab = &As[p][wm][0];
    const u16* Wb = &Ws[p][0];

    short8 af[4][2], bf[2][2];
    // B frags (cols wn*32 + {0,16}), reused across both phases
#pragma unroll
    for (int ni = 0; ni < 2; ++ni)
#pragma unroll
      for (int ks = 0; ks < 2; ++ks) {
        int rh = wn * 32 + ni * 16 + l15;
        bf[ni][ks] = *(const short8*)&Wb[rh * 64 + (((ks * 4 + lh) ^ (rh & 7)) << 3)];
      }
    // ---- phase 0: A lo half
#pragma unroll
    for (int mi = 0; mi < 4; ++mi)
#pragma unroll
      for (int ks = 0; ks < 2; ++ks) {
        int rh = mi * 16 + l15;
        af[mi][ks] = *(const short8*)&Ab[rh * 64 + (((ks * 4 + lh) ^ (rh & 7)) << 3)];
      }
    __builtin_amdgcn_s_setprio(1);
#pragma unroll
    for (int mi = 0; mi < 4; ++mi)
#pragma unroll
      for (int ni = 0; ni < 2; ++ni)
#pragma unroll
        for (int ks = 0; ks < 2; ++ks)
          acc[mi][ni] = mfma_bf16(af[mi][ks], bf[ni][ks], acc[mi][ni]);
    __builtin_amdgcn_s_setprio(0);
    __builtin_amdgcn_s_barrier();
    // ---- phase 1: A hi half
#pragma unroll
    for (int mi = 0; mi < 4; ++mi)
#pragma unroll
      for (int ks = 0; ks < 2; ++ks) {
        int rh = (4 + mi) * 16 + l15;
        af[mi][ks] = *(const short8*)&Ab[rh * 64 + (((ks * 4 + lh) ^ (rh & 7)) << 3)];
      }
    __builtin_amdgcn_s_setprio(1);
#pragma unroll
    for (int mi = 0; mi < 4; ++mi)
#pragma unroll
      for (int ni = 0; ni < 2; ++ni)
#pragma unroll
        for (int ks = 0; ks < 2; ++ks)
          acc[4 + mi][ni] = mfma_bf16(af[mi][ks], bf[ni][ks], acc[4 + mi][ni]);
    __builtin_amdgcn_s_setprio(0);

    // B2: all reads of buf[p] complete before next iter's issue overwrites it
    asm volatile("s_waitcnt lgkmcnt(0)" ::: "memory");
    __builtin_amdgcn_sched_barrier(0);
    __builtin_amdgcn_s_barrier();
    __builtin_amdgcn_sched_barrier(0);
  }

  // ---- epilogue (fp32)
#pragma unroll
  for (int mi = 0; mi < 8; ++mi)
#pragma unroll
    for (int ni = 0; ni < 2; ++ni)
#pragma unroll
      for (int j = 0; j < 4; ++j) {
        int row = brow + wm * 128 + mi * 16 + lh * 4 + j;
        int col = bcol + wn * 32 + ni * 16 + l15;
        C[(size_t)row * N + col] = acc[mi][ni][j];
      }
}

// ---------- fused causal GQA flash attention (R9, unchanged) ----------
#define QBLK 128
#define KVBLK 128

static __device__ __forceinline__ void attn_tile(
    const short8* qa, f32x4* o, float& l, float& m,
    int qrow0, int kv0,
    const u16* Ks, const unsigned* Vt32, u16* myP,
    int l15, int lh) {
  if (kv0 > qrow0 + 15) return;   // fully masked for this wave

  // ---- swapped QK^T: st[nt][j] = S[kv = kv0+nt*16+lh*4+j][q = qrow0+l15]
  f32x4 st[4];
#pragma unroll
  for (int nt = 0; nt < 4; ++nt) st[nt] = (f32x4)0.0f;
  __builtin_amdgcn_s_setprio(1);
#pragma unroll
  for (int nt = 0; nt < 4; ++nt) {
    const u16* krow = &Ks[(nt * 16 + l15) * 136 + (lh << 3)];
#pragma unroll
    for (int kk = 0; kk < 4; ++kk) {
      short8 kb = *(const short8*)(krow + kk * 32);
      st[nt] = mfma_bf16(kb, qa[kk], st[nt]);
    }
  }
  __builtin_amdgcn_s_setprio(0);

  // ---- causal mask: kv > q  <=>  (kv0 + lh*4 - qrow0 - l15) + nt*16 + j > 0
  const int kvq = kv0 + lh * 4 - qrow0 - l15;
#pragma unroll
  for (int nt = 0; nt < 4; ++nt)
#pragma unroll
    for (int j = 0; j < 4; ++j)
      if (kvq + nt * 16 + j > 0) st[nt][j] = -1e30f;

  // ---- in-lane row max (q = l15), then reduce across the 4 lh groups
  float mt = st[0][0];
#pragma unroll
  for (int nt = 0; nt < 4; ++nt)
#pragma unroll
    for (int j = 0; j < 4; ++j) mt = fmaxf(mt, st[nt][j]);
  mt = fmaxf(mt, __shfl_xor(mt, 16));
  mt = fmaxf(mt, __shfl_xor(mt, 32));

  // ---- defer-max (T13): rescale only when max grew by > 8
  if (!__all(mt - m <= 8.0f)) {
    float mn = fmaxf(m, mt);
    float a = __expf(m - mn);
    m = mn;
    l *= a;
    float aj[4];
#pragma unroll
    for (int j = 0; j < 4; ++j) aj[j] = __shfl(a, lh * 4 + j);
#pragma unroll
    for (int n = 0; n < 8; ++n)
#pragma unroll
      for (int j = 0; j < 4; ++j) o[n][j] *= aj[j];
  }

  // ---- P = exp(S - m); row-sum accumulated in-lane (partial over this lh)
  f32x4 p[4];
  float ps = 0.0f;
#pragma unroll
  for (int nt = 0; nt < 4; ++nt) {
#pragma unroll
    for (int j = 0; j < 4; ++j) p[nt][j] = __expf(st[nt][j] - m);
    ps += (p[nt][0] + p[nt][1]) + (p[nt][2] + p[nt][3]);
  }
  l += ps;

  // ---- P -> per-wave LDS, pair-packed b32 at elem l15*72 + kv
  unsigned* P32 = (unsigned*)myP;
  const int pb = l15 * 36 + lh * 2;
#pragma unroll
  for (int nt = 0; nt < 4; ++nt)
#pragma unroll
    for (int jj = 0; jj < 2; ++jj)
      P32[pb + nt * 8 + jj] =
          (unsigned)f2b(p[nt][2 * jj]) | ((unsigned)f2b(p[nt][2 * jj + 1]) << 16);

  // ---- PV (read pattern unchanged from verified kernel)
  __builtin_amdgcn_s_setprio(1);
#pragma unroll
  for (int c = 0; c < 2; ++c) {
    short8 pa = *(const short8*)&myP[l15 * 72 + c * 32 + (lh << 3)];
#pragma unroll
    for (int nt2 = 0; nt2 < 8; ++nt2) {
      int d = nt2 * 16 + l15;
      int byteoff = (d * 144 + (c * 32 + lh * 8) * 2) ^ (((d >> 3) & 7) << 4);
      short8 vb = *(const short8*)((const char*)Vt32 + byteoff);
      o[nt2] = mfma_bf16(pa, vb, o[nt2]);
    }
  }
  __builtin_amdgcn_s_setprio(0);
}

__global__ __launch_bounds__(512) void attn_kernel(const u16* __restrict__ QKV,
                                                   const float* __restrict__ rope,
                                                   u16* __restrict__ Y) {
  __shared__ __align__(16) u16 Ks[2][64 * 136];        // 2 x 17408 B
  __shared__ __align__(16) unsigned Vt32[2][128 * 36]; // 2 x 18432 B
  __shared__ __align__(16) u16 Ps[8][16 * 72];         // 18432 B

  const int tid = threadIdx.x, lane = tid & 63, wid = tid >> 6;
  const int l15 = lane & 15, lh = lane >> 4;
  const int bid = blockIdx.x;
  const int qpair = bid & 7;
  const int h = (bid >> 3) & 15;
  const int b = bid >> 7;
  const int kvh = h >> 2;
  const int qtA = qpair, qtB = 15 - qpair;
  const int rowA = qtA * QBLK + wid * 16;
  const int rowB = qtB * QBLK + wid * 16;

  const u16* Kb_ = QKV + (size_t)b * TT * QSTR + DD + kvh * HD;  // K cols
  const u16* Vb_ = Kb_ + NKVH * HD;                              // V cols

  short8 qaA[4], qaB[4];
  {
    const u16* qA = QKV + (size_t)(b * TT + rowA + l15) * QSTR + h * HD + (lh << 3);
    const u16* qB = QKV + (size_t)(b * TT + rowB + l15) * QSTR + h * HD + (lh << 3);
#pragma unroll
    for (int kk = 0; kk < 4; ++kk) {
      qaA[kk] = *(const short8*)(qA + kk * 32);
      qaB[kk] = *(const short8*)(qB + kk * 32);
    }
  }
  // ---- fused Q-RoPE + softmax scale (pair (i, i+64) = qa[kk] / qa[kk+2])
  {
    const float* rpA = rope + (size_t)(rowA + l15) * 128;
    const float* rpB = rope + (size_t)(rowB + l15) * 128;
#pragma unroll
    for (int kk = 0; kk < 2; ++kk)
#pragma unroll
      for (int e = 0; e < 8; ++e) {
        const int i2 = 2 * (kk * 32 + (lh << 3) + e);
        float c = rpA[i2], s = rpA[i2 + 1];
        float x1 = b2f((u16)qaA[kk][e]), x2 = b2f((u16)qaA[kk + 2][e]);
        qaA[kk][e]     = (short)f2b(QSCALE * (x1 * c - x2 * s));
        qaA[kk + 2][e] = (short)f2b(QSCALE * (x1 * s + x2 * c));
        float cb = rpB[i2], sb = rpB[i2 + 1];
        float y1 = b2f((u16)qaB[kk][e]), y2 = b2f((u16)qaB[kk + 2][e]);
        qaB[kk][e]     = (short)f2b(QSCALE * (y1 * cb - y2 * sb));
        qaB[kk + 2][e] = (short)f2b(QSCALE * (y1 * sb + y2 * cb));
      }
  }

  f32x4 oA[8], oB[8];
  float lA = 0.0f, lB = 0.0f;
  float mA = -1e30f, mB = -1e30f;
#pragma unroll
  for (int n = 0; n < 8; ++n) { oA[n] = (f32x4)0.0f; oB[n] = (f32x4)0.0f; }

  const int kvend = (qtB + 1) * QBLK;   // multiple of 128

  // staging registers (T14: issue early, write late); 128 KV rows per pass
  short8 kreg[4], vreg[4];
  const int srow = tid >> 4;           // 0..31
  const int sc8 = (tid & 15) << 3;

  auto issue = [&](int kv0) {
    kreg[0] = *(const short8*)&Kb_[(size_t)(kv0 + srow) * QSTR + sc8];
    kreg[1] = *(const short8*)&Kb_[(size_t)(kv0 + 32 + srow) * QSTR + sc8];
    kreg[2] = *(const short8*)&Kb_[(size_t)(kv0 + 64 + srow) * QSTR + sc8];
    kreg[3] = *(const short8*)&Kb_[(size_t)(kv0 + 96 + srow) * QSTR + sc8];
    vreg[0] = *(const short8*)&Vb_[(size_t)(kv0 + 2 * srow) * QSTR + sc8];
    vreg[1] = *(const short8*)&Vb_[(size_t)(kv0 + 2 * srow + 1) * QSTR + sc8];
    vreg[2] = *(const short8*)&Vb_[(size_t)(kv0 + 64 + 2 * srow) * QSTR + sc8];
    vreg[3] = *(const short8*)&Vb_[(size_t)(kv0 + 64 + 2 * srow + 1) * QSTR + sc8];
  };

  issue(0);
  for (int kv0 = 0; kv0 < kvend; kv0 += KVBLK) {
    __syncthreads();   // previous tile's LDS reads done
    *(short8*)&Ks[0][srow * 136 + sc8] = kreg[0];
    *(short8*)&Ks[0][(srow + 32) * 136 + sc8] = kreg[1];
    *(short8*)&Ks[1][srow * 136 + sc8] = kreg[2];
    *(short8*)&Ks[1][(srow + 32) * 136 + sc8] = kreg[3];
#pragma unroll
    for (int e = 0; e < 8; ++e) {
      int d = sc8 + e;
      unsigned pk0 = (unsigned)(u16)vreg[0][e] | ((unsigned)(u16)vreg[1][e] << 16);
      unsigned pk1 = (unsigned)(u16)vreg[2][e] | ((unsigned)(u16)vreg[3][e] << 16);
      int byteoff = (d * 144 + 4 * srow) ^ (((d >> 3) & 7) << 4);
      *(unsigned*)((char*)&Vt32[0][0] + byteoff) = pk0;
      *(unsigned*)((char*)&Vt32[1][0] + byteoff) = pk1;
    }
    __syncthreads();   // staged tile visible
    if (kv0 + KVBLK < kvend) issue(kv0 + KVBLK);  // overlap next loads with compute

    attn_tile(qaA, oA, lA, mA, rowA, kv0,      &Ks[0][0], &Vt32[0][0], &Ps[wid][0], l15, lh);
    attn_tile(qaA, oA, lA, mA, rowA, kv0 + 64, &Ks[1][0], &Vt32[1][0], &Ps[wid][0], l15, lh);
    attn_tile(qaB, oB, lB, mB, rowB, kv0,      &Ks[0][0], &Vt32[0][0], &Ps[wid][0], l15, lh);
    attn_tile(qaB, oB, lB, mB, rowB, kv0 + 64, &Ks[1][0], &Vt32[1][0], &Ps[wid][0], l15, lh);
  }

  // ---- epilogue: total row-sums (reduce over lh), redistribute to q=lh*4+j
  lA += __shfl_xor(lA, 16); lA += __shfl_xor(lA, 32);
  lB += __shfl_xor(lB, 16); lB += __shfl_xor(lB, 32);
  f32x4 invA, invB;
#pragma unroll
  for (int j = 0; j < 4; ++j) {
    invA[j] = __builtin_amdgcn_rcpf(__shfl(lA, lh * 4 + j));
    invB[j] = __builtin_amdgcn_rcpf(__shfl(lB, lh * 4 + j));
  }
#pragma unroll
  for (int nt = 0; nt < 8; ++nt)
#pragma unroll
    for (int j = 0; j < 4; ++j) {
      Y[(size_t)(b * TT + rowA + lh * 4 + j) * DD + h * HD + nt * 16 + l15] =
          f2b(oA[nt][j] * invA[j]);
      Y[(size_t)(b * TT + rowB + lh * 4 + j) * DD + h * HD + nt * 16 + l15] =
          f2b(oB[nt][j] * invB[j]);
    }
}

// ---------- launcher ----------
extern "C" void kernel_launch(void* const* d_in, const int* in_sizes, int n_in,
                              void* d_out, int out_size, void* d_ws, size_t ws_size,
                              hipStream_t stream) {
  const float* x    = (const float*)d_in[0];
  const float* rope = (const float*)d_in[1];
  const float* wq   = (const float*)d_in[2];
  const float* wk   = (const float*)d_in[3];
  const float* wv   = (const float*)d_in[4];
  const float* wo   = (const float*)d_in[5];
  float* out = (float*)d_out;

  char* ws = (char*)d_ws;
  u16* xb    = (u16*)ws; ws += (size_t)MM * DD * 2;        // 16.8 MB
  u16* wqkvb = (u16*)ws; ws += (size_t)QSTR * DD * 2;      // 12.6 MB (wq|wk|wv rows)
  u16* wob   = (u16*)ws; ws += (size_t)DD * DD * 2;        //  8.4 MB
  u16* QKVb  = (u16*)ws; ws += (size_t)MM * QSTR * 2;      // 25.2 MB
  u16* Yb    = (u16*)ws;                                   // 16.8 MB

  // 1) fused converts: x, wq, wk, wv, wo in ONE launch
  cvt_all<<<2048, 256, 0, stream>>>(x, wq, wk, wv, wo, xb, wqkvb, wob);

  // 2) fused QKV projection: 256x192 counted-vmcnt GEMM (256 blocks, 1/CU)
  gemm_qkv<<<dim3(QSTR / 192, MM / 256), 512, 0, stream>>>(xb, wqkvb, QKVb, MM, QSTR, DD);

  // 3) RoPE on K only (Q-rope fused into attention)
  rope_k<<<(MM * NKVH * 64) / 256, 256, 0, stream>>>(QKVb + DD, rope);

  // 4) attention (swapped-QK^T softmax path)
  attn_kernel<<<BB * NH * (TT / QBLK / 2), 512, 0, stream>>>(QKVb, rope, Yb);

  // 5) output projection: 256x128 counted-vmcnt GEMM (256 blocks, 1/CU)
  gemm_wo<<<dim3(DD / 128, MM / 256), 512, 0, stream>>>(Yb, wob, out, MM, DD, DD);
}

// Round 12
// 199.726 us; speedup vs baseline: 1.1365x; 1.0016x over previous
//
#include <hip/hip_runtime.h>

// ---------- types & helpers ----------
typedef unsigned short u16;
typedef float   f32x4  __attribute__((ext_vector_type(4)));
typedef short   short8 __attribute__((ext_vector_type(8)));
typedef __bf16  bf16x8 __attribute__((ext_vector_type(8)));
typedef float   float4v __attribute__((ext_vector_type(4)));
typedef unsigned short u16x4 __attribute__((ext_vector_type(4)));

// native HW bf16 convert (RNE) — do not hand-roll (T12/m240)
static __device__ __forceinline__ u16 f2b(float f) {
  return __builtin_bit_cast(u16, (__bf16)f);
}
static __device__ __forceinline__ float b2f(u16 h) {
  union { unsigned u; float f; } v; v.u = ((unsigned)h) << 16;
  return v.f;
}
static __device__ __forceinline__ f32x4 mfma_bf16(short8 a, short8 b, f32x4 c) {
  return __builtin_amdgcn_mfma_f32_16x16x32_bf16(
      __builtin_bit_cast(bf16x8, a), __builtin_bit_cast(bf16x8, b), c, 0, 0, 0);
}
// async global->LDS, 16B per lane; lds ptr must be wave-uniform base (HW adds lane*16)
static __device__ __forceinline__ void gload_lds16(const u16* g, u16* l) {
  __builtin_amdgcn_global_load_lds(
      (const __attribute__((address_space(1))) unsigned int*)g,
      (__attribute__((address_space(3))) unsigned int*)l, 16, 0, 0);
}

// ---------- problem constants ----------
#define BB 2
#define TT 2048
#define DD 2048
#define NH 16
#define NKVH 4
#define HD 128
#define MM (BB * TT)          // 4096 rows
#define QSTR 3072             // fused QKV projection row: [Q(2048) | K(512) | V(512)]
#define QSCALE 0.08838834764831845f

// ---------- fused fp32 -> bf16 convert (all 5 tensors, 1 launch) ----------
#define N4_X   ((MM * DD) / 4)
#define N4_WQ  ((DD * DD) / 4)
#define N4_WKV ((NKVH * HD * DD) / 4)
#define N4_WO  ((DD * DD) / 4)
#define N4_TOT (N4_X + N4_WQ + 2 * N4_WKV + N4_WO)

__global__ __launch_bounds__(256) void cvt_all(const float* __restrict__ x,
                                               const float* __restrict__ wq,
                                               const float* __restrict__ wk,
                                               const float* __restrict__ wv,
                                               const float* __restrict__ wo,
                                               u16* __restrict__ xb,
                                               u16* __restrict__ wqkvb,
                                               u16* __restrict__ wob) {
  int stride = gridDim.x * blockDim.x;
  for (int i = blockIdx.x * blockDim.x + threadIdx.x; i < N4_TOT; i += stride) {
    const float4v* src;
    u16x4* dst;
    int off;
    if (i < N4_X) {
      src = (const float4v*)x; dst = (u16x4*)xb; off = i;
    } else if (i < N4_X + N4_WQ) {
      src = (const float4v*)wq; dst = (u16x4*)wqkvb; off = i - N4_X;
    } else if (i < N4_X + N4_WQ + N4_WKV) {
      src = (const float4v*)wk; dst = (u16x4*)wqkvb + N4_WQ; off = i - (N4_X + N4_WQ);
    } else if (i < N4_X + N4_WQ + 2 * N4_WKV) {
      src = (const float4v*)wv; dst = (u16x4*)wqkvb + N4_WQ + N4_WKV;
      off = i - (N4_X + N4_WQ + N4_WKV);
    } else {
      src = (const float4v*)wo; dst = (u16x4*)wob; off = i - (N4_X + N4_WQ + 2 * N4_WKV);
    }
    float4v v = src[off];
    u16x4 o;
    o[0] = f2b(v[0]); o[1] = f2b(v[1]); o[2] = f2b(v[2]); o[3] = f2b(v[3]);
    dst[off] = o;
  }
}

// ---------- RoPE on K only (Q-rope is fused into the attention prologue) ----------
__global__ __launch_bounds__(256) void rope_k(u16* __restrict__ K,
                                              const float* __restrict__ rope) {
  int idx = blockIdx.x * 256 + threadIdx.x;
  int i  = idx & 63;
  int h  = (idx >> 6) & (NKVH - 1);
  int bt = idx >> 8;
  int t  = bt & (TT - 1);
  size_t base = (size_t)bt * QSTR + h * HD + i;
  float x1 = b2f(K[base]);
  float x2 = b2f(K[base + 64]);
  float c = rope[t * 128 + 2 * i];
  float s = rope[t * 128 + 2 * i + 1];
  K[base]      = f2b(x1 * c - x2 * s);
  K[base + 64] = f2b(x1 * s + x2 * c);
}

// ---------- 256x192 counted-vmcnt GEMM (QKV projection, bf16 out) ----------
__global__ __launch_bounds__(512) void gemm_qkv(const u16* __restrict__ A,
                                                const u16* __restrict__ W,
                                                u16* __restrict__ C,
                                                int M, int N, int K) {
  __shared__ __align__(16) u16 As[2][2][128 * 64];  // [buf][half][r*64+swz] 64KB
  __shared__ __align__(16) u16 Ws[2][192 * 64];     // [buf][r*64+swz]       48KB

  const int tid = threadIdx.x, lane = tid & 63, wid = tid >> 6;
  const int wm = wid >> 2, wn = wid & 3;
  const int l15 = lane & 15, lh = lane >> 4;

  // T1 bijective XCD swizzle (nwg = 256, %8 == 0)
  const int nwg = gridDim.x * gridDim.y;
  const int lin = blockIdx.y * gridDim.x + blockIdx.x;
  const int swz = (lin & 7) * (nwg >> 3) + (lin >> 3);
  const int brow = (swz / gridDim.x) * 256, bcol = (swz % gridDim.x) * 192;

  const int srp = wid * 8 + (lane >> 3);
  const int gsw = ((lane & 7) ^ (lane >> 3)) << 3;
  const u16* sa[2][2];
  const u16* sw3[3];
#pragma unroll
  for (int mh = 0; mh < 2; ++mh)
#pragma unroll
    for (int i = 0; i < 2; ++i)
      sa[mh][i] = A + (size_t)(brow + mh * 128 + i * 64 + srp) * K + gsw;
#pragma unroll
  for (int i = 0; i < 3; ++i)
    sw3[i] = W + (size_t)(bcol + i * 64 + srp) * K + gsw;

  f32x4 acc[8][3];
#pragma unroll
  for (int mi = 0; mi < 8; ++mi)
#pragma unroll
    for (int ni = 0; ni < 3; ++ni) acc[mi][ni] = (f32x4)0.0f;

  const int nk = K >> 6;  // 64-wide K tiles

  auto issue = [&](int t, int p) {
#pragma unroll
    for (int mh = 0; mh < 2; ++mh)
#pragma unroll
      for (int i = 0; i < 2; ++i)
        gload_lds16(sa[mh][i] + t * 64, &As[p][mh][i * 4096 + wid * 512]);
#pragma unroll
    for (int i = 0; i < 3; ++i)
      gload_lds16(sw3[i] + t * 64, &Ws[p][i * 4096 + wid * 512]);
  };

  issue(0, 0);
  for (int t = 0; t < nk; ++t) {
    const int p = t & 1;
    if (t + 1 < nk) {
      issue(t + 1, p ^ 1);  // next tile: 7 loads stay in flight across compute
      asm volatile("s_waitcnt vmcnt(7)" ::: "memory");  // tile t's 7 landed
    } else {
      asm volatile("s_waitcnt vmcnt(0)" ::: "memory");
    }
    __builtin_amdgcn_sched_barrier(0);
    __builtin_amdgcn_s_barrier();   // B1: all waves' tile-t stages visible
    __builtin_amdgcn_sched_barrier(0);

    const u16* Ab = &As[p][wm][0];
    const u16* Wb = &Ws[p][0];

    short8 af[4][2], bf[3][2];
    // B frags (cols wn*48 + {0,16,32}), reused across both phases
#pragma unroll
    for (int ni = 0; ni < 3; ++ni)
#pragma unroll
      for (int ks = 0; ks < 2; ++ks) {
        int rh = wn * 48 + ni * 16 + l15;
        bf[ni][ks] = *(const short8*)&Wb[rh * 64 + (((ks * 4 + lh) ^ (rh & 7)) << 3)];
      }
    // ---- phase 0: A lo half
#pragma unroll
    for (int mi = 0; mi < 4; ++mi)
#pragma unroll
      for (int ks = 0; ks < 2; ++ks) {
        int rh = mi * 16 + l15;
        af[mi][ks] = *(const short8*)&Ab[rh * 64 + (((ks * 4 + lh) ^ (rh & 7)) << 3)];
      }
    __builtin_amdgcn_s_setprio(1);
#pragma unroll
    for (int mi = 0; mi < 4; ++mi)
#pragma unroll
      for (int ni = 0; ni < 3; ++ni)
#pragma unroll
        for (int ks = 0; ks < 2; ++ks)
          acc[mi][ni] = mfma_bf16(af[mi][ks], bf[ni][ks], acc[mi][ni]);
    __builtin_amdgcn_s_setprio(0);
    __builtin_amdgcn_s_barrier();
    // ---- phase 1: A hi half
#pragma unroll
    for (int mi = 0; mi < 4; ++mi)
#pragma unroll
      for (int ks = 0; ks < 2; ++ks) {
        int rh = (4 + mi) * 16 + l15;
        af[mi][ks] = *(const short8*)&Ab[rh * 64 + (((ks * 4 + lh) ^ (rh & 7)) << 3)];
      }
    __builtin_amdgcn_s_setprio(1);
#pragma unroll
    for (int mi = 0; mi < 4; ++mi)
#pragma unroll
      for (int ni = 0; ni < 3; ++ni)
#pragma unroll
        for (int ks = 0; ks < 2; ++ks)
          acc[4 + mi][ni] = mfma_bf16(af[mi][ks], bf[ni][ks], acc[4 + mi][ni]);
    __builtin_amdgcn_s_setprio(0);

    // B2: all reads of buf[p] complete before next iter's issue overwrites it
    asm volatile("s_waitcnt lgkmcnt(0)" ::: "memory");
    __builtin_amdgcn_sched_barrier(0);
    __builtin_amdgcn_s_barrier();
    __builtin_amdgcn_sched_barrier(0);
  }

  // ---- epilogue (bf16)
#pragma unroll
  for (int mi = 0; mi < 8; ++mi)
#pragma unroll
    for (int ni = 0; ni < 3; ++ni)
#pragma unroll
      for (int j = 0; j < 4; ++j) {
        int row = brow + wm * 128 + mi * 16 + lh * 4 + j;
        int col = bcol + wn * 48 + ni * 16 + l15;
        C[(size_t)row * N + col] = f2b(acc[mi][ni][j]);
      }
}

// ---------- 256x128 counted-vmcnt GEMM (WO projection, fp32 out) ----------
__global__ __launch_bounds__(512, 2) void gemm_wo(const u16* __restrict__ A,
                                                  const u16* __restrict__ W,
                                                  float* __restrict__ C,
                                                  int M, int N, int K) {
  __shared__ __align__(16) u16 As[2][2][128 * 64];  // [buf][half][r*64+swz] 64KB
  __shared__ __align__(16) u16 Ws[2][128 * 64];     // [buf][r*64+swz]       32KB

  const int tid = threadIdx.x, lane = tid & 63, wid = tid >> 6;
  const int wm = wid >> 2, wn = wid & 3;
  const int l15 = lane & 15, lh = lane >> 4;

  // T1 bijective XCD swizzle (nwg = 256, %8 == 0)
  const int nwg = gridDim.x * gridDim.y;
  const int lin = blockIdx.y * gridDim.x + blockIdx.x;
  const int swz = (lin & 7) * (nwg >> 3) + (lin >> 3);
  const int brow = (swz / gridDim.x) * 256, bcol = (swz % gridDim.x) * 128;

  const int srp = wid * 8 + (lane >> 3);
  const int gsw = ((lane & 7) ^ (lane >> 3)) << 3;
  const u16* sa[2][2];
  const u16* sw2[2];
#pragma unroll
  for (int mh = 0; mh < 2; ++mh)
#pragma unroll
    for (int i = 0; i < 2; ++i)
      sa[mh][i] = A + (size_t)(brow + mh * 128 + i * 64 + srp) * K + gsw;
#pragma unroll
  for (int i = 0; i < 2; ++i)
    sw2[i] = W + (size_t)(bcol + i * 64 + srp) * K + gsw;

  f32x4 acc[8][2];
#pragma unroll
  for (int mi = 0; mi < 8; ++mi)
#pragma unroll
    for (int ni = 0; ni < 2; ++ni) acc[mi][ni] = (f32x4)0.0f;

  const int nk = K >> 6;

  auto issue = [&](int t, int p) {
#pragma unroll
    for (int mh = 0; mh < 2; ++mh)
#pragma unroll
      for (int i = 0; i < 2; ++i)
        gload_lds16(sa[mh][i] + t * 64, &As[p][mh][i * 4096 + wid * 512]);
#pragma unroll
    for (int i = 0; i < 2; ++i)
      gload_lds16(sw2[i] + t * 64, &Ws[p][i * 4096 + wid * 512]);
  };

  issue(0, 0);
  for (int t = 0; t < nk; ++t) {
    const int p = t & 1;
    if (t + 1 < nk) {
      issue(t + 1, p ^ 1);  // 6 loads for tile t+1 stay in flight
      asm volatile("s_waitcnt vmcnt(6)" ::: "memory");  // tile t's 6 landed
    } else {
      asm volatile("s_waitcnt vmcnt(0)" ::: "memory");
    }
    __builtin_amdgcn_sched_barrier(0);
    __builtin_amdgcn_s_barrier();   // B1: tile-t stages visible
    __builtin_amdgcn_sched_barrier(0);

    const u16* Ab = &As[p][wm][0];
    const u16* Wb = &Ws[p][0];

    short8 af[4][2], bf[2][2];
    // B frags (cols wn*32 + {0,16}), reused across both phases
#pragma unroll
    for (int ni = 0; ni < 2; ++ni)
#pragma unroll
      for (int ks = 0; ks < 2; ++ks) {
        int rh = wn * 32 + ni * 16 + l15;
        bf[ni][ks] = *(const short8*)&Wb[rh * 64 + (((ks * 4 + lh) ^ (rh & 7)) << 3)];
      }
    // ---- phase 0: A lo half
#pragma unroll
    for (int mi = 0; mi < 4; ++mi)
#pragma unroll
      for (int ks = 0; ks < 2; ++ks) {
        int rh = mi * 16 + l15;
        af[mi][ks] = *(const short8*)&Ab[rh * 64 + (((ks * 4 + lh) ^ (rh & 7)) << 3)];
      }
    __builtin_amdgcn_s_setprio(1);
#pragma unroll
    for (int mi = 0; mi < 4; ++mi)
#pragma unroll
      for (int ni = 0; ni < 2; ++ni)
#pragma unroll
        for (int ks = 0; ks < 2; ++ks)
          acc[mi][ni] = mfma_bf16(af[mi][ks], bf[ni][ks], acc[mi][ni]);
    __builtin_amdgcn_s_setprio(0);
    __builtin_amdgcn_s_barrier();
    // ---- phase 1: A hi half
#pragma unroll
    for (int mi = 0; mi < 4; ++mi)
#pragma unroll
      for (int ks = 0; ks < 2; ++ks) {
        int rh = (4 + mi) * 16 + l15;
        af[mi][ks] = *(const short8*)&Ab[rh * 64 + (((ks * 4 + lh) ^ (rh & 7)) << 3)];
      }
    __builtin_amdgcn_s_setprio(1);
#pragma unroll
    for (int mi = 0; mi < 4; ++mi)
#pragma unroll
      for (int ni = 0; ni < 2; ++ni)
#pragma unroll
        for (int ks = 0; ks < 2; ++ks)
          acc[4 + mi][ni] = mfma_bf16(af[mi][ks], bf[ni][ks], acc[4 + mi][ni]);
    __builtin_amdgcn_s_setprio(0);

    // B2: all reads of buf[p] complete before next iter's issue overwrites it
    asm volatile("s_waitcnt lgkmcnt(0)" ::: "memory");
    __builtin_amdgcn_sched_barrier(0);
    __builtin_amdgcn_s_barrier();
    __builtin_amdgcn_sched_barrier(0);
  }

  // ---- epilogue (fp32)
#pragma unroll
  for (int mi = 0; mi < 8; ++mi)
#pragma unroll
    for (int ni = 0; ni < 2; ++ni)
#pragma unroll
      for (int j = 0; j < 4; ++j) {
        int row = brow + wm * 128 + mi * 16 + lh * 4 + j;
        int col = bcol + wn * 32 + ni * 16 + l15;
        C[(size_t)row * N + col] = acc[mi][ni][j];
      }
}

// ---------- fused causal GQA flash attention ----------
// R11 shell unchanged (256 blocks x 8 waves, paired q-tiles, T14 staging,
// KVBLK=128, swapped QK^T). NEW (T15 + frag-share): the A and B q-tile
// streams are processed in ONE merged call per 64-row sub-tile with
// per-stream P buffers (PA/PB):
//   * each K fragment read once, feeds mfma(kb,qaA) AND mfma(kb,qaB)
//   * each V fragment read once, feeds both PV streams
//   -> K/V LDS reads/iter/wave 96 -> 64 b128 (-33%)
//   * distinct PA/PB remove the LDS alias that serialized calls; the
//     A-softmax VALU can overlap B's independent MFMAs (T15 mechanism)
// qtA < qtB always => actA implies actB (wave-uniform guards).
#define QBLK 128
#define KVBLK 128

static __device__ __forceinline__ void attn_tile2(
    const short8* qaA, const short8* qaB,
    f32x4* oA, f32x4* oB, float& lA_, float& lB_, float& mA_, float& mB_,
    int rowA, int rowB, int kv0,
    const u16* Ks, const unsigned* Vt32, u16* PA, u16* PB,
    int l15, int lh) {
  if (kv0 > rowB + 15) return;            // both masked (rowA < rowB)
  const bool actA = (kv0 <= rowA + 15);   // wave-uniform

  // ---- swapped QK^T, K fragments shared: st[nt][j] = S[kv][q=l15]
  f32x4 stA[4], stB[4];
#pragma unroll
  for (int nt = 0; nt < 4; ++nt) { stA[nt] = (f32x4)0.0f; stB[nt] = (f32x4)0.0f; }
  __builtin_amdgcn_s_setprio(1);
  if (actA) {
#pragma unroll
    for (int nt = 0; nt < 4; ++nt) {
      const u16* krow = &Ks[(nt * 16 + l15) * 136 + (lh << 3)];
#pragma unroll
      for (int kk = 0; kk < 4; ++kk) {
        short8 kb = *(const short8*)(krow + kk * 32);
        stB[nt] = mfma_bf16(kb, qaB[kk], stB[nt]);
        stA[nt] = mfma_bf16(kb, qaA[kk], stA[nt]);
      }
    }
  } else {
#pragma unroll
    for (int nt = 0; nt < 4; ++nt) {
      const u16* krow = &Ks[(nt * 16 + l15) * 136 + (lh << 3)];
#pragma unroll
      for (int kk = 0; kk < 4; ++kk) {
        short8 kb = *(const short8*)(krow + kk * 32);
        stB[nt] = mfma_bf16(kb, qaB[kk], stB[nt]);
      }
    }
  }
  __builtin_amdgcn_s_setprio(0);

  // ---- stream B softmax (mask, in-lane max, defer-max, exp, P-write)
  {
    const int kvq = kv0 + lh * 4 - rowB - l15;
#pragma unroll
    for (int nt = 0; nt < 4; ++nt)
#pragma unroll
      for (int j = 0; j < 4; ++j)
        if (kvq + nt * 16 + j > 0) stB[nt][j] = -1e30f;
    float mt = stB[0][0];
#pragma unroll
    for (int nt = 0; nt < 4; ++nt)
#pragma unroll
      for (int j = 0; j < 4; ++j) mt = fmaxf(mt, stB[nt][j]);
    mt = fmaxf(mt, __shfl_xor(mt, 16));
    mt = fmaxf(mt, __shfl_xor(mt, 32));
    if (!__all(mt - mB_ <= 8.0f)) {
      float mn = fmaxf(mB_, mt);
      float a = __expf(mB_ - mn);
      mB_ = mn;
      lB_ *= a;
      float aj[4];
#pragma unroll
      for (int j = 0; j < 4; ++j) aj[j] = __shfl(a, lh * 4 + j);
#pragma unroll
      for (int n = 0; n < 8; ++n)
#pragma unroll
        for (int j = 0; j < 4; ++j) oB[n][j] *= aj[j];
    }
    f32x4 p[4];
    float ps = 0.0f;
#pragma unroll
    for (int nt = 0; nt < 4; ++nt) {
#pragma unroll
      for (int j = 0; j < 4; ++j) p[nt][j] = __expf(stB[nt][j] - mB_);
      ps += (p[nt][0] + p[nt][1]) + (p[nt][2] + p[nt][3]);
    }
    lB_ += ps;
    unsigned* P32 = (unsigned*)PB;
    const int pb = l15 * 36 + lh * 2;
#pragma unroll
    for (int nt = 0; nt < 4; ++nt)
#pragma unroll
      for (int jj = 0; jj < 2; ++jj)
        P32[pb + nt * 8 + jj] =
            (unsigned)f2b(p[nt][2 * jj]) | ((unsigned)f2b(p[nt][2 * jj + 1]) << 16);
  }

  // ---- stream A softmax
  if (actA) {
    const int kvq = kv0 + lh * 4 - rowA - l15;
#pragma unroll
    for (int nt = 0; nt < 4; ++nt)
#pragma unroll
      for (int j = 0; j < 4; ++j)
        if (kvq + nt * 16 + j > 0) stA[nt][j] = -1e30f;
    float mt = stA[0][0];
#pragma unroll
    for (int nt = 0; nt < 4; ++nt)
#pragma unroll
      for (int j = 0; j < 4; ++j) mt = fmaxf(mt, stA[nt][j]);
    mt = fmaxf(mt, __shfl_xor(mt, 16));
    mt = fmaxf(mt, __shfl_xor(mt, 32));
    if (!__all(mt - mA_ <= 8.0f)) {
      float mn = fmaxf(mA_, mt);
      float a = __expf(mA_ - mn);
      mA_ = mn;
      lA_ *= a;
      float aj[4];
#pragma unroll
      for (int j = 0; j < 4; ++j) aj[j] = __shfl(a, lh * 4 + j);
#pragma unroll
      for (int n = 0; n < 8; ++n)
#pragma unroll
        for (int j = 0; j < 4; ++j) oA[n][j] *= aj[j];
    }
    f32x4 p[4];
    float ps = 0.0f;
#pragma unroll
    for (int nt = 0; nt < 4; ++nt) {
#pragma unroll
      for (int j = 0; j < 4; ++j) p[nt][j] = __expf(stA[nt][j] - mA_);
      ps += (p[nt][0] + p[nt][1]) + (p[nt][2] + p[nt][3]);
    }
    lA_ += ps;
    unsigned* P32 = (unsigned*)PA;
    const int pb = l15 * 36 + lh * 2;
#pragma unroll
    for (int nt = 0; nt < 4; ++nt)
#pragma unroll
      for (int jj = 0; jj < 2; ++jj)
        P32[pb + nt * 8 + jj] =
            (unsigned)f2b(p[nt][2 * jj]) | ((unsigned)f2b(p[nt][2 * jj + 1]) << 16);
  }

  // ---- PV, V fragments shared across streams
  __builtin_amdgcn_s_setprio(1);
  if (actA) {
#pragma unroll
    for (int c = 0; c < 2; ++c) {
      short8 paB = *(const short8*)&PB[l15 * 72 + c * 32 + (lh << 3)];
      short8 paA = *(const short8*)&PA[l15 * 72 + c * 32 + (lh << 3)];
#pragma unroll
      for (int nt2 = 0; nt2 < 8; ++nt2) {
        int d = nt2 * 16 + l15;
        int byteoff = (d * 144 + (c * 32 + lh * 8) * 2) ^ (((d >> 3) & 7) << 4);
        short8 vb = *(const short8*)((const char*)Vt32 + byteoff);
        oB[nt2] = mfma_bf16(paB, vb, oB[nt2]);
        oA[nt2] = mfma_bf16(paA, vb, oA[nt2]);
      }
    }
  } else {
#pragma unroll
    for (int c = 0; c < 2; ++c) {
      short8 paB = *(const short8*)&PB[l15 * 72 + c * 32 + (lh << 3)];
#pragma unroll
      for (int nt2 = 0; nt2 < 8; ++nt2) {
        int d = nt2 * 16 + l15;
        int byteoff = (d * 144 + (c * 32 + lh * 8) * 2) ^ (((d >> 3) & 7) << 4);
        short8 vb = *(const short8*)((const char*)Vt32 + byteoff);
        oB[nt2] = mfma_bf16(paB, vb, oB[nt2]);
      }
    }
  }
  __builtin_amdgcn_s_setprio(0);
}

__global__ __launch_bounds__(512) void attn_kernel(const u16* __restrict__ QKV,
                                                   const float* __restrict__ rope,
                                                   u16* __restrict__ Y) {
  __shared__ __align__(16) u16 Ks[2][64 * 136];        // 2 x 17408 B
  __shared__ __align__(16) unsigned Vt32[2][128 * 36]; // 2 x 18432 B
  __shared__ __align__(16) u16 Ps[8][2][16 * 72];      // 36864 B
  // total 108544 B -> 1 block/CU

  const int tid = threadIdx.x, lane = tid & 63, wid = tid >> 6;
  const int l15 = lane & 15, lh = lane >> 4;
  const int bid = blockIdx.x;
  const int qpair = bid & 7;
  const int h = (bid >> 3) & 15;
  const int b = bid >> 7;
  const int kvh = h >> 2;
  const int qtA = qpair, qtB = 15 - qpair;
  const int rowA = qtA * QBLK + wid * 16;
  const int rowB = qtB * QBLK + wid * 16;

  const u16* Kb_ = QKV + (size_t)b * TT * QSTR + DD + kvh * HD;  // K cols
  const u16* Vb_ = Kb_ + NKVH * HD;                              // V cols

  short8 qaA[4], qaB[4];
  {
    const u16* qA = QKV + (size_t)(b * TT + rowA + l15) * QSTR + h * HD + (lh << 3);
    const u16* qB = QKV + (size_t)(b * TT + rowB + l15) * QSTR + h * HD + (lh << 3);
#pragma unroll
    for (int kk = 0; kk < 4; ++kk) {
      qaA[kk] = *(const short8*)(qA + kk * 32);
      qaB[kk] = *(const short8*)(qB + kk * 32);
    }
  }
  // ---- fused Q-RoPE + softmax scale (pair (i, i+64) = qa[kk] / qa[kk+2])
  {
    const float* rpA = rope + (size_t)(rowA + l15) * 128;
    const float* rpB = rope + (size_t)(rowB + l15) * 128;
#pragma unroll
    for (int kk = 0; kk < 2; ++kk)
#pragma unroll
      for (int e = 0; e < 8; ++e) {
        const int i2 = 2 * (kk * 32 + (lh << 3) + e);
        float c = rpA[i2], s = rpA[i2 + 1];
        float x1 = b2f((u16)qaA[kk][e]), x2 = b2f((u16)qaA[kk + 2][e]);
        qaA[kk][e]     = (short)f2b(QSCALE * (x1 * c - x2 * s));
        qaA[kk + 2][e] = (short)f2b(QSCALE * (x1 * s + x2 * c));
        float cb = rpB[i2], sb = rpB[i2 + 1];
        float y1 = b2f((u16)qaB[kk][e]), y2 = b2f((u16)qaB[kk + 2][e]);
        qaB[kk][e]     = (short)f2b(QSCALE * (y1 * cb - y2 * sb));
        qaB[kk + 2][e] = (short)f2b(QSCALE * (y1 * sb + y2 * cb));
      }
  }

  f32x4 oA[8], oB[8];
  float lA = 0.0f, lB = 0.0f;
  float mA = -1e30f, mB = -1e30f;
#pragma unroll
  for (int n = 0; n < 8; ++n) { oA[n] = (f32x4)0.0f; oB[n] = (f32x4)0.0f; }

  const int kvend = (qtB + 1) * QBLK;   // multiple of 128

  // staging registers (T14: issue early, write late); 128 KV rows per pass
  short8 kreg[4], vreg[4];
  const int srow = tid >> 4;           // 0..31
  const int sc8 = (tid & 15) << 3;

  auto issue = [&](int kv0) {
    kreg[0] = *(const short8*)&Kb_[(size_t)(kv0 + srow) * QSTR + sc8];
    kreg[1] = *(const short8*)&Kb_[(size_t)(kv0 + 32 + srow) * QSTR + sc8];
    kreg[2] = *(const short8*)&Kb_[(size_t)(kv0 + 64 + srow) * QSTR + sc8];
    kreg[3] = *(const short8*)&Kb_[(size_t)(kv0 + 96 + srow) * QSTR + sc8];
    vreg[0] = *(const short8*)&Vb_[(size_t)(kv0 + 2 * srow) * QSTR + sc8];
    vreg[1] = *(const short8*)&Vb_[(size_t)(kv0 + 2 * srow + 1) * QSTR + sc8];
    vreg[2] = *(const short8*)&Vb_[(size_t)(kv0 + 64 + 2 * srow) * QSTR + sc8];
    vreg[3] = *(const short8*)&Vb_[(size_t)(kv0 + 64 + 2 * srow + 1) * QSTR + sc8];
  };

  issue(0);
  for (int kv0 = 0; kv0 < kvend; kv0 += KVBLK) {
    __syncthreads();   // previous tile's LDS reads done
    *(short8*)&Ks[0][srow * 136 + sc8] = kreg[0];
    *(short8*)&Ks[0][(srow + 32) * 136 + sc8] = kreg[1];
    *(short8*)&Ks[1][srow * 136 + sc8] = kreg[2];
    *(short8*)&Ks[1][(srow + 32) * 136 + sc8] = kreg[3];
#pragma unroll
    for (int e = 0; e < 8; ++e) {
      int d = sc8 + e;
      unsigned pk0 = (unsigned)(u16)vreg[0][e] | ((unsigned)(u16)vreg[1][e] << 16);
      unsigned pk1 = (unsigned)(u16)vreg[2][e] | ((unsigned)(u16)vreg[3][e] << 16);
      int byteoff = (d * 144 + 4 * srow) ^ (((d >> 3) & 7) << 4);
      *(unsigned*)((char*)&Vt32[0][0] + byteoff) = pk0;
      *(unsigned*)((char*)&Vt32[1][0] + byteoff) = pk1;
    }
    __syncthreads();   // staged tile visible
    if (kv0 + KVBLK < kvend) issue(kv0 + KVBLK);  // overlap next loads with compute

    attn_tile2(qaA, qaB, oA, oB, lA, lB, mA, mB, rowA, rowB, kv0,
               &Ks[0][0], &Vt32[0][0], &Ps[wid][0][0], &Ps[wid][1][0], l15, lh);
    attn_tile2(qaA, qaB, oA, oB, lA, lB, mA, mB, rowA, rowB, kv0 + 64,
               &Ks[1][0], &Vt32[1][0], &Ps[wid][0][0], &Ps[wid][1][0], l15, lh);
  }

  // ---- epilogue: total row-sums (reduce over lh), redistribute to q=lh*4+j
  lA += __shfl_xor(lA, 16); lA += __shfl_xor(lA, 32);
  lB += __shfl_xor(lB, 16); lB += __shfl_xor(lB, 32);
  f32x4 invA, invB;
#pragma unroll
  for (int j = 0; j < 4; ++j) {
    invA[j] = __builtin_amdgcn_rcpf(__shfl(lA, lh * 4 + j));
    invB[j] = __builtin_amdgcn_rcpf(__shfl(lB, lh * 4 + j));
  }
#pragma unroll
  for (int nt = 0; nt < 8; ++nt)
#pragma unroll
    for (int j = 0; j < 4; ++j) {
      Y[(size_t)(b * TT + rowA + lh * 4 + j) * DD + h * HD + nt * 16 + l15] =
          f2b(oA[nt][j] * invA[j]);
      Y[(size_t)(b * TT + rowB + lh * 4 + j) * DD + h * HD + nt * 16 + l15] =
          f2b(oB[nt][j] * invB[j]);
    }
}

// ---------- launcher ----------
extern "C" void kernel_launch(void* const* d_in, const int* in_sizes, int n_in,
                              void* d_out, int out_size, void* d_ws, size_t ws_size,
                              hipStream_t stream) {
  const float* x    = (const float*)d_in[0];
  const float* rope = (const float*)d_in[1];
  const float* wq   = (const float*)d_in[2];
  const float* wk   = (const float*)d_in[3];
  const float* wv   = (const float*)d_in[4];
  const float* wo   = (const float*)d_in[5];
  float* out = (float*)d_out;

  char* ws = (char*)d_ws;
  u16* xb    = (u16*)ws; ws += (size_t)MM * DD * 2;        // 16.8 MB
  u16* wqkvb = (u16*)ws; ws += (size_t)QSTR * DD * 2;      // 12.6 MB (wq|wk|wv rows)
  u16* wob   = (u16*)ws; ws += (size_t)DD * DD * 2;        //  8.4 MB
  u16* QKVb  = (u16*)ws; ws += (size_t)MM * QSTR * 2;      // 25.2 MB
  u16* Yb    = (u16*)ws;                                   // 16.8 MB

  // 1) fused converts: x, wq, wk, wv, wo in ONE launch
  cvt_all<<<2048, 256, 0, stream>>>(x, wq, wk, wv, wo, xb, wqkvb, wob);

  // 2) fused QKV projection: 256x192 counted-vmcnt GEMM (256 blocks, 1/CU)
  gemm_qkv<<<dim3(QSTR / 192, MM / 256), 512, 0, stream>>>(xb, wqkvb, QKVb, MM, QSTR, DD);

  // 3) RoPE on K only (Q-rope fused into attention)
  rope_k<<<(MM * NKVH * 64) / 256, 256, 0, stream>>>(QKVb + DD, rope);

  // 4) attention (merged A/B streams, shared K/V frags, per-stream P)
  attn_kernel<<<BB * NH * (TT / QBLK / 2), 512, 0, stream>>>(QKVb, rope, Yb);

  // 5) output projection: 256x128 counted-vmcnt GEMM (256 blocks, 1/CU)
  gemm_wo<<<dim3(DD / 128, MM / 256), 512, 0, stream>>>(Yb, wob, out, MM, DD, DD);
}